// Round 2
// baseline (21503.378 us; speedup 1.0000x reference)
//
#include <hip/hip_runtime.h>
#include <cmath>

#define BB 8
#define NN 2048
#define CC 512
#define NITER 3
#define MP 516
#define AUGCOL 512

// workspace layout (units: floats); all double regions 8B-aligned (even offsets)
static constexpr size_t G_OFF  = 0;                          // f32 [B][3][C][C]
static constexpr size_t G_SZ   = (size_t)BB*3*CC*CC;         // 6291456
static constexpr size_t M_OFF  = G_OFF + G_SZ;               // f64 [B][C][MP]
static constexpr size_t M_SZF  = (size_t)BB*CC*MP*2;         // 4227072 floats
static constexpr size_t T_OFF  = M_OFF + M_SZF;              // f64 [B][C][MP]
static constexpr size_t DF_OFF = T_OFF + M_SZF;              // f64 [B][C][3]
static constexpr size_t DF_SZF = (size_t)BB*CC*3*2;
static constexpr size_t LMD_OFF= DF_OFF + DF_SZF;            // f64 [B][C]
static constexpr size_t LMD_SZF= (size_t)BB*CC*2;
static constexpr size_t PERM_OFF = LMD_OFF + LMD_SZF;        // int [B][C]
static constexpr size_t PERM_SZ  = (size_t)BB*CC;
static constexpr size_t PART_OFF = PERM_OFF + PERM_SZ;       // f32 [8][B][6144]

// ---------------------------------------------------------------------------
// G[b][d][c][c'] = jacp[b,c',i_c,d]/m_i - jacp[b,c',j_c,d]/m_j (f64 math, f32
// store); diff0 (f64); zero lambda (f64).   grid (512 c, 8 b) x 256
__global__ void k_gbuild(const float* __restrict__ pos, const float* __restrict__ mas,
                         const float* __restrict__ jacp, const int* __restrict__ pi,
                         const int* __restrict__ pj, float* __restrict__ ws)
{
    const int c = blockIdx.x, b = blockIdx.y, t = threadIdx.x;
    const int i = pi[c], j = pj[c];
    const double im = 1.0 / (double)mas[b*NN + i];
    const double jm = 1.0 / (double)mas[b*NN + j];
    float* G = ws + G_OFF;
    const float* Ji = jacp + ((size_t)b*CC*NN + i)*3;
    const float* Jj = jacp + ((size_t)b*CC*NN + j)*3;
    for (int cp = t; cp < CC; cp += 256){
        const size_t o = (size_t)cp*NN*3;
        const size_t gb = ((size_t)(b*3+0)*CC + c)*CC + cp;
        G[gb]                   = (float)((double)Ji[o+0]*im - (double)Jj[o+0]*jm);
        G[gb + (size_t)CC*CC]   = (float)((double)Ji[o+1]*im - (double)Jj[o+1]*jm);
        G[gb + (size_t)2*CC*CC] = (float)((double)Ji[o+2]*im - (double)Jj[o+2]*jm);
    }
    if (t == 0){
        double* df = (double*)(ws + DF_OFF) + ((size_t)b*CC + c)*3;
        for (int d = 0; d < 3; ++d)
            df[d] = (double)pos[((size_t)b*NN+i)*3+d] - (double)pos[((size_t)b*NN+j)*3+d];
    }
    if (c == 0){
        double* l = (double*)(ws + LMD_OFF) + (size_t)b*CC;
        l[t] = 0.0; l[t+256] = 0.0;
    }
}

// ---------------------------------------------------------------------------
// y = G.lmd (f64 accum), dif = diff0 - dt2*y, M[c][c'] = -2dt2*sum_d dif_d*G,
// M[c][512] = |dif|^2 - d0.   grid (512 c, 8 b) x 256
__global__ void k_build(const float* __restrict__ d0v, const float* __restrict__ dtm,
                        float* __restrict__ ws)
{
    const int c = blockIdx.x, b = blockIdx.y, t = threadIdx.x;
    const float* G = ws + G_OFF;
    const double* l = (const double*)(ws + LMD_OFF) + (size_t)b*CC;
    const double dt = (double)dtm[b], dt2 = dt*dt;
    const size_t g0 = ((size_t)(b*3+0)*CC + c)*CC;
    const size_t g1 = g0 + (size_t)CC*CC;
    const size_t g2 = g0 + (size_t)2*CC*CC;
    const int c1 = t, c2 = t + 256;
    const double l1 = l[c1], l2 = l[c2];
    const double ga0 = (double)G[g0+c1], gb0 = (double)G[g0+c2];
    const double ga1 = (double)G[g1+c1], gb1 = (double)G[g1+c2];
    const double ga2 = (double)G[g2+c1], gb2 = (double)G[g2+c2];
    double p0 = ga0*l1 + gb0*l2;
    double p1 = ga1*l1 + gb1*l2;
    double p2 = ga2*l1 + gb2*l2;
    __shared__ double red[12];
    #pragma unroll
    for (int off = 32; off; off >>= 1){
        p0 += __shfl_xor(p0, off);
        p1 += __shfl_xor(p1, off);
        p2 += __shfl_xor(p2, off);
    }
    if ((t & 63) == 0){ const int w = t>>6; red[w*3+0]=p0; red[w*3+1]=p1; red[w*3+2]=p2; }
    __syncthreads();
    const double y0 = red[0]+red[3]+red[6]+red[9];
    const double y1 = red[1]+red[4]+red[7]+red[10];
    const double y2 = red[2]+red[5]+red[8]+red[11];
    const double* df = (const double*)(ws + DF_OFF) + ((size_t)b*CC + c)*3;
    const double e0 = df[0] - dt2*y0;
    const double e1 = df[1] - dt2*y1;
    const double e2 = df[2] - dt2*y2;
    const double s = -2.0*dt2;
    double* Mrow = (double*)(ws + M_OFF) + ((size_t)b*CC + c)*MP;
    Mrow[c1] = s*(e0*ga0 + e1*ga1 + e2*ga2);
    Mrow[c2] = s*(e0*gb0 + e1*gb1 + e2*gb2);
    if (t == 0) Mrow[AUGCOL] = e0*e0 + e1*e1 + e2*e2 - (double)d0v[c];
}

// ---------------------------------------------------------------------------
// f64 panel factorization with partial pivoting (rows in registers),
// writes back panel + perm.   grid (8 b) x 256
__global__ __launch_bounds__(256, 1) void k_panel(float* __restrict__ ws, int kb)
{
    const int b = blockIdx.x, t = threadIdx.x;
    const int m = CC - kb*64, base = kb*64;
    double* M = (double*)(ws + M_OFF) + (size_t)b*CC*MP;

    __shared__ double bufA[64];
    __shared__ double bufB[64];
    __shared__ double wv[4];
    __shared__ int    wi[4];
    __shared__ int    perm[CC];

    const bool h0 = (t < m), h1 = (t + 256 < m);
    double r0[64], r1[64];
    if (h0){
        const double* sp = M + (size_t)(base + t)*MP + base;
        #pragma unroll
        for (int j = 0; j < 64; ++j) r0[j] = sp[j];
    }
    if (h1){
        const double* sp = M + (size_t)(base + t + 256)*MP + base;
        #pragma unroll
        for (int j = 0; j < 64; ++j) r1[j] = sp[j];
    }
    perm[t] = t; perm[t+256] = t+256;
    __syncthreads();

    #pragma unroll
    for (int k = 0; k < 64; ++k){
        // ---- pivot search on column k (first-max like LAPACK) ----
        const double v0 = (h0 && t >= k) ? fabs(r0[k]) : -1.0;
        const double v1 = h1 ? fabs(r1[k]) : -1.0;
        double vmax = fmax(v0, v1);
        #pragma unroll
        for (int off = 32; off; off >>= 1){
            const double o = __shfl_xor(vmax, off);
            vmax = fmax(vmax, o);
        }
        int idx = 1 << 20;
        if (v0 >= 0.0 && v0 == vmax) idx = t;
        else if (v1 >= 0.0 && v1 == vmax) idx = t + 256;
        #pragma unroll
        for (int off = 32; off; off >>= 1){
            const int o = __shfl_xor(idx, off);
            idx = min(idx, o);
        }
        if ((t & 63) == 0){ wv[t>>6] = vmax; wi[t>>6] = idx; }
        __syncthreads();
        const double gv = fmax(fmax(wv[0], wv[1]), fmax(wv[2], wv[3]));
        int lb = 1 << 20;
        #pragma unroll
        for (int w = 0; w < 4; ++w) if (wv[w] == gv) lb = min(lb, wi[w]);
        // ---- exchange rows k <-> lb (bufB holds the pivot row) ----
        if (lb != k && t == k){
            #pragma unroll
            for (int j = 0; j < 64; ++j) bufA[j] = r0[j];
        }
        if (t == lb){
            #pragma unroll
            for (int j = 0; j < 64; ++j) bufB[j] = r0[j];
        }
        if (t + 256 == lb){
            #pragma unroll
            for (int j = 0; j < 64; ++j) bufB[j] = r1[j];
        }
        if (t == 0 && lb != k){ const int tp = perm[k]; perm[k] = perm[lb]; perm[lb] = tp; }
        __syncthreads();
        if (lb != k){
            if (t == k){
                #pragma unroll
                for (int j = 0; j < 64; ++j) r0[j] = bufB[j];
            }
            if (t == lb){
                #pragma unroll
                for (int j = 0; j < 64; ++j) r0[j] = bufA[j];
            }
            if (t + 256 == lb){
                #pragma unroll
                for (int j = 0; j < 64; ++j) r1[j] = bufA[j];
            }
        }
        const double pv = bufB[k];
        // ---- scale + rank-1 update (rows > k) ----
        if (h0 && t > k){
            const double ml = r0[k] / pv; r0[k] = ml;
            #pragma unroll
            for (int j = k+1; j < 64; ++j) r0[j] = fma(-ml, bufB[j], r0[j]);
        }
        if (h1){
            const double ml = r1[k] / pv; r1[k] = ml;
            #pragma unroll
            for (int j = k+1; j < 64; ++j) r1[j] = fma(-ml, bufB[j], r1[j]);
        }
    }

    if (h0){
        double* dp = M + (size_t)(base + t)*MP + base;
        #pragma unroll
        for (int j = 0; j < 64; ++j) dp[j] = r0[j];
    }
    if (h1){
        double* dp = M + (size_t)(base + t + 256)*MP + base;
        #pragma unroll
        for (int j = 0; j < 64; ++j) dp[j] = r1[j];
    }
    int* gp = (int*)(ws + PERM_OFF) + b*CC;
    if (t < m) gp[t] = perm[t];
    if (t + 256 < m) gp[t+256] = perm[t+256];
}

// ---------------------------------------------------------------------------
// Per 32-col stripe: permute U12 rows to LDS + A22 rows to T, then TRSM
// (forward substitution with unit-lower L), write U12 back.
// grid (2*(7-kb)+1 stripes, 8 b) x 256
__global__ __launch_bounds__(256) void k_apply(float* __restrict__ ws, int kb)
{
    const int sx = blockIdx.x, b = blockIdx.y, t = threadIdx.x;
    const int nfull = 2*(7 - kb);
    const bool isaug = (sx == nfull);
    const int cs = isaug ? AUGCOL : (kb+1)*64 + sx*32;
    const int W  = isaug ? 1 : 32;
    const int m = CC - kb*64, base = kb*64;
    double* M = (double*)(ws + M_OFF) + (size_t)b*CC*MP;
    double* T = (double*)(ws + T_OFF) + (size_t)b*CC*MP;
    const int* perm = (const int*)(ws + PERM_OFF) + b*CC;

    __shared__ double LT[64][66];   // LT[s][i] = L[i][s]
    __shared__ double Bs[64][34];

    for (int idx = t; idx < 4096; idx += 256){
        const int i = idx >> 6, s = idx & 63;
        LT[s][i] = M[(size_t)(base+i)*MP + base + s];
    }
    const int c = t & 31, rg = t >> 5;
    for (int i = rg; i < 64; i += 8)
        if (c < W) Bs[i][c] = M[(size_t)(base + perm[i])*MP + cs + c];
    for (int l = 64 + rg; l < m; l += 8)
        if (c < W) T[(size_t)(base+l)*MP + cs + c] = M[(size_t)(base+perm[l])*MP + cs + c];
    __syncthreads();

    for (int s = 0; s < 63; ++s){
        const double bsc = (c < W) ? Bs[s][c] : 0.0;
        #pragma unroll
        for (int i0 = 0; i0 < 8; ++i0){
            const int i = i0*8 + rg;
            if (i > s && c < W) Bs[i][c] = fma(-LT[s][i], bsc, Bs[i][c]);
        }
        __syncthreads();
    }

    for (int i = rg; i < 64; i += 8)
        if (c < W) M[(size_t)(base+i)*MP + cs + c] = Bs[i][c];
}

// ---------------------------------------------------------------------------
// Trailing update: M[rows][stripe] = T[rows][stripe] - L21*U12 (f64, K=2x32)
// grid (7-kb rt, 8-kb sx, 8 b) x 256
__global__ __launch_bounds__(256) void k_gemm(float* __restrict__ ws, int kb)
{
    const int rt = blockIdx.x, sx = blockIdx.y, b = blockIdx.z, t = threadIdx.x;
    const int nfull = 7 - kb;
    const bool isaug = (sx == nfull);
    const int cs = isaug ? AUGCOL : (kb+1+sx)*64;
    const int W  = isaug ? 1 : 64;
    const int base = kb*64;
    const int gr0 = base + 64 + rt*64;
    double* M = (double*)(ws + M_OFF) + (size_t)b*CC*MP;
    double* T = (double*)(ws + T_OFF) + (size_t)b*CC*MP;

    __shared__ double LTc[32][66];  // LTc[kk][r] = L21[gr0+r][base+ch*32+kk]
    __shared__ double Uc [32][66];  // Uc[kk][c]  = U12[base+ch*32+kk][cs+c]

    const int rq = t >> 4, cq = t & 15;
    double acc[4][4] = {};
    for (int ch = 0; ch < 2; ++ch){
        __syncthreads();
        for (int idx = t; idx < 2048; idx += 256){
            const int r = idx >> 5, kk = idx & 31;
            LTc[kk][r] = M[(size_t)(gr0+r)*MP + base + ch*32 + kk];
        }
        for (int idx = t; idx < 2048; idx += 256){
            const int rr2 = idx >> 6, cc2 = idx & 63;
            Uc[rr2][cc2] = (cc2 < W) ? M[(size_t)(base + ch*32 + rr2)*MP + cs + cc2] : 0.0;
        }
        __syncthreads();
        for (int kk = 0; kk < 32; ++kk){
            const double lv0 = LTc[kk][rq*4+0], lv1 = LTc[kk][rq*4+1];
            const double lv2 = LTc[kk][rq*4+2], lv3 = LTc[kk][rq*4+3];
            const double uv0 = Uc[kk][cq*4+0], uv1 = Uc[kk][cq*4+1];
            const double uv2 = Uc[kk][cq*4+2], uv3 = Uc[kk][cq*4+3];
            acc[0][0]=fma(lv0,uv0,acc[0][0]); acc[0][1]=fma(lv0,uv1,acc[0][1]);
            acc[0][2]=fma(lv0,uv2,acc[0][2]); acc[0][3]=fma(lv0,uv3,acc[0][3]);
            acc[1][0]=fma(lv1,uv0,acc[1][0]); acc[1][1]=fma(lv1,uv1,acc[1][1]);
            acc[1][2]=fma(lv1,uv2,acc[1][2]); acc[1][3]=fma(lv1,uv3,acc[1][3]);
            acc[2][0]=fma(lv2,uv0,acc[2][0]); acc[2][1]=fma(lv2,uv1,acc[2][1]);
            acc[2][2]=fma(lv2,uv2,acc[2][2]); acc[2][3]=fma(lv2,uv3,acc[2][3]);
            acc[3][0]=fma(lv3,uv0,acc[3][0]); acc[3][1]=fma(lv3,uv1,acc[3][1]);
            acc[3][2]=fma(lv3,uv2,acc[3][2]); acc[3][3]=fma(lv3,uv3,acc[3][3]);
        }
    }
    #pragma unroll
    for (int i = 0; i < 4; ++i)
        #pragma unroll
        for (int j = 0; j < 4; ++j){
            const int c2 = cq*4 + j;
            if (c2 < W){
                const size_t o = (size_t)(gr0 + rq*4 + i)*MP + cs + c2;
                M[o] = T[o] - acc[i][j];
            }
        }
}

// ---------------------------------------------------------------------------
// Back-substitution on U with eliminated aug column; lmd -= delta. grid (8 b)
__global__ __launch_bounds__(256) void k_backsub(float* __restrict__ ws)
{
    const int b = blockIdx.x, t = threadIdx.x;
    double* M = (double*)(ws + M_OFF) + (size_t)b*CC*MP;
    __shared__ double y[CC];
    __shared__ double Ud[64][65];
    y[t]     = M[(size_t)t*MP + AUGCOL];
    y[t+256] = M[(size_t)(t+256)*MP + AUGCOL];
    __syncthreads();
    for (int sb = 7; sb >= 0; --sb){
        const int rb = sb*64;
        for (int idx = t; idx < 4096; idx += 256)
            Ud[idx>>6][idx&63] = M[(size_t)(rb + (idx>>6))*MP + rb + (idx&63)];
        __syncthreads();
        if (t < 64){
            double yv = y[rb + t];
            for (int kk = 63; kk >= 0; --kk){
                double xk = __shfl(yv, kk);
                xk = xk / Ud[kk][kk];
                if (t == kk) yv = xk;
                else if (t < kk) yv = fma(-Ud[t][kk], xk, yv);
            }
            y[rb + t] = yv;
        }
        __syncthreads();
        for (int r = t; r < rb; r += 256){
            const double* Mr = M + (size_t)r*MP + rb;
            double sacc = 0.0;
            for (int j = 0; j < 64; ++j) sacc = fma(Mr[j], y[rb + j], sacc);
            y[r] -= sacc;
        }
        __syncthreads();
    }
    double* l = (double*)(ws + LMD_OFF) + (size_t)b*CC;
    l[t]     -= y[t];
    l[t+256] -= y[t+256];
}

// ---------------------------------------------------------------------------
// Split-K partial of sum_c lmd*jacp (f64 accum, f32 store).
// grid (24 nb, 8 b, 8 kc) x 256
__global__ void k_frc(const float* __restrict__ jacp, float* __restrict__ ws)
{
    const int nb = blockIdx.x, b = blockIdx.y, kc = blockIdx.z, t = threadIdx.x;
    const int nd = nb*256 + t;
    const double* l = (const double*)(ws + LMD_OFF) + (size_t)b*CC + kc*64;
    const float* J = jacp + ((size_t)(b*CC + kc*64))*NN*3 + nd;
    double acc = 0.0;
    for (int c2 = 0; c2 < 64; ++c2) acc = fma(l[c2], (double)J[(size_t)c2*NN*3], acc);
    ws[PART_OFF + ((size_t)kc*8 + b)*6144 + nd] = (float)acc;
}

// ---------------------------------------------------------------------------
// Combine partials, write pos_new, mom_new, lmd.  grid (208) x 256
__global__ void k_out(const float* __restrict__ pos, const float* __restrict__ mom,
                      const float* __restrict__ mas, const float* __restrict__ dtm,
                      const float* __restrict__ ws, float* __restrict__ out)
{
    const int wg = blockIdx.x, t = threadIdx.x;
    if (wg < 192){
        const int b = wg / 24, nb = wg % 24;
        const int nd = nb*256 + t;
        float sacc = 0.f;
        for (int kc = 0; kc < 8; ++kc) sacc += ws[PART_OFF + ((size_t)kc*8 + b)*6144 + nd];
        const float frc = -sacc;
        const int n = nd / 3;
        const float dt = dtm[b], dt2 = dt*dt;
        out[(size_t)b*6144 + nd]         = pos[(size_t)b*6144 + nd] + frc / mas[b*NN + n] * dt2;
        out[49152 + (size_t)b*6144 + nd] = mom[(size_t)b*6144 + nd] + frc * dt;
    } else {
        const int idx = (wg - 192)*256 + t;      // 0..4095
        out[98304 + idx] = (float)(((const double*)(ws + LMD_OFF))[idx]);
    }
}

// ---------------------------------------------------------------------------
extern "C" void kernel_launch(void* const* d_in, const int* in_sizes, int n_in,
                              void* d_out, int out_size, void* d_ws, size_t ws_size,
                              hipStream_t stream)
{
    (void)in_sizes; (void)n_in; (void)out_size; (void)ws_size;
    const float* pos  = (const float*)d_in[0];
    const float* mom  = (const float*)d_in[1];
    const float* mas  = (const float*)d_in[2];
    const float* dtm  = (const float*)d_in[3];
    const float* jacp = (const float*)d_in[4];
    const int*   pi   = (const int*)d_in[5];
    const int*   pj   = (const int*)d_in[6];
    const float* d0v  = (const float*)d_in[7];
    float* ws  = (float*)d_ws;
    float* out = (float*)d_out;

    k_gbuild<<<dim3(CC, BB), 256, 0, stream>>>(pos, mas, jacp, pi, pj, ws);
    for (int it = 0; it < NITER; ++it){
        k_build<<<dim3(CC, BB), 256, 0, stream>>>(d0v, dtm, ws);
        for (int kb = 0; kb < 8; ++kb){
            k_panel<<<dim3(BB), 256, 0, stream>>>(ws, kb);
            k_apply<<<dim3(2*(7-kb)+1, BB), 256, 0, stream>>>(ws, kb);
            if (kb < 7)
                k_gemm<<<dim3(7-kb, 8-kb, BB), 256, 0, stream>>>(ws, kb);
        }
        k_backsub<<<dim3(BB), 256, 0, stream>>>(ws);
    }
    k_frc<<<dim3(24, BB, 8), 256, 0, stream>>>(jacp, ws);
    k_out<<<dim3(208), 256, 0, stream>>>(pos, mom, mas, dtm, ws, out);
}

// Round 3
// 18353.163 us; speedup vs baseline: 1.1716x; 1.1716x over previous
//
#include <hip/hip_runtime.h>
#include <cmath>

#define BB 8
#define NN 2048
#define CC 512
#define NITER 3
#define MP 516
#define AUGCOL 512

// workspace layout (units: floats); all double regions 8B-aligned (even offsets)
static constexpr size_t G_OFF  = 0;                          // f32 [B][3][C][C]
static constexpr size_t G_SZ   = (size_t)BB*3*CC*CC;         // 6291456
static constexpr size_t M_OFF  = G_OFF + G_SZ;               // f64 [B][C][MP]
static constexpr size_t M_SZF  = (size_t)BB*CC*MP*2;         // 4227072 floats
static constexpr size_t T_OFF  = M_OFF + M_SZF;              // f64 [B][C][MP]
static constexpr size_t DF_OFF = T_OFF + M_SZF;              // f64 [B][C][3]
static constexpr size_t DF_SZF = (size_t)BB*CC*3*2;
static constexpr size_t LMD_OFF= DF_OFF + DF_SZF;            // f64 [B][C]
static constexpr size_t LMD_SZF= (size_t)BB*CC*2;
static constexpr size_t PERM_OFF = LMD_OFF + LMD_SZF;        // int [B][C]
static constexpr size_t PERM_SZ  = (size_t)BB*CC;
static constexpr size_t PART_OFF = PERM_OFF + PERM_SZ;       // f32 [8][B][6144]

// ---------------------------------------------------------------------------
// G[b][d][c][c'] = jacp[b,c',i_c,d]/m_i - jacp[b,c',j_c,d]/m_j (f64 math, f32
// store); diff0 (f64); zero lambda (f64).   grid (512 c, 8 b) x 256
__global__ void k_gbuild(const float* __restrict__ pos, const float* __restrict__ mas,
                         const float* __restrict__ jacp, const int* __restrict__ pi,
                         const int* __restrict__ pj, float* __restrict__ ws)
{
    const int c = blockIdx.x, b = blockIdx.y, t = threadIdx.x;
    const int i = pi[c], j = pj[c];
    const double im = 1.0 / (double)mas[b*NN + i];
    const double jm = 1.0 / (double)mas[b*NN + j];
    float* G = ws + G_OFF;
    const float* Ji = jacp + ((size_t)b*CC*NN + i)*3;
    const float* Jj = jacp + ((size_t)b*CC*NN + j)*3;
    for (int cp = t; cp < CC; cp += 256){
        const size_t o = (size_t)cp*NN*3;
        const size_t gb = ((size_t)(b*3+0)*CC + c)*CC + cp;
        G[gb]                   = (float)((double)Ji[o+0]*im - (double)Jj[o+0]*jm);
        G[gb + (size_t)CC*CC]   = (float)((double)Ji[o+1]*im - (double)Jj[o+1]*jm);
        G[gb + (size_t)2*CC*CC] = (float)((double)Ji[o+2]*im - (double)Jj[o+2]*jm);
    }
    if (t == 0){
        double* df = (double*)(ws + DF_OFF) + ((size_t)b*CC + c)*3;
        for (int d = 0; d < 3; ++d)
            df[d] = (double)pos[((size_t)b*NN+i)*3+d] - (double)pos[((size_t)b*NN+j)*3+d];
    }
    if (c == 0){
        double* l = (double*)(ws + LMD_OFF) + (size_t)b*CC;
        l[t] = 0.0; l[t+256] = 0.0;
    }
}

// ---------------------------------------------------------------------------
// y = G.lmd (f64 accum), dif = diff0 - dt2*y, M[c][c'] = -2dt2*sum_d dif_d*G,
// M[c][512] = |dif|^2 - d0.   grid (512 c, 8 b) x 256
__global__ void k_build(const float* __restrict__ d0v, const float* __restrict__ dtm,
                        float* __restrict__ ws)
{
    const int c = blockIdx.x, b = blockIdx.y, t = threadIdx.x;
    const float* G = ws + G_OFF;
    const double* l = (const double*)(ws + LMD_OFF) + (size_t)b*CC;
    const double dt = (double)dtm[b], dt2 = dt*dt;
    const size_t g0 = ((size_t)(b*3+0)*CC + c)*CC;
    const size_t g1 = g0 + (size_t)CC*CC;
    const size_t g2 = g0 + (size_t)2*CC*CC;
    const int c1 = t, c2 = t + 256;
    const double l1 = l[c1], l2 = l[c2];
    const double ga0 = (double)G[g0+c1], gb0 = (double)G[g0+c2];
    const double ga1 = (double)G[g1+c1], gb1 = (double)G[g1+c2];
    const double ga2 = (double)G[g2+c1], gb2 = (double)G[g2+c2];
    double p0 = ga0*l1 + gb0*l2;
    double p1 = ga1*l1 + gb1*l2;
    double p2 = ga2*l1 + gb2*l2;
    __shared__ double red[12];
    #pragma unroll
    for (int off = 32; off; off >>= 1){
        p0 += __shfl_xor(p0, off);
        p1 += __shfl_xor(p1, off);
        p2 += __shfl_xor(p2, off);
    }
    if ((t & 63) == 0){ const int w = t>>6; red[w*3+0]=p0; red[w*3+1]=p1; red[w*3+2]=p2; }
    __syncthreads();
    const double y0 = red[0]+red[3]+red[6]+red[9];
    const double y1 = red[1]+red[4]+red[7]+red[10];
    const double y2 = red[2]+red[5]+red[8]+red[11];
    const double* df = (const double*)(ws + DF_OFF) + ((size_t)b*CC + c)*3;
    const double e0 = df[0] - dt2*y0;
    const double e1 = df[1] - dt2*y1;
    const double e2 = df[2] - dt2*y2;
    const double s = -2.0*dt2;
    double* Mrow = (double*)(ws + M_OFF) + ((size_t)b*CC + c)*MP;
    Mrow[c1] = s*(e0*ga0 + e1*ga1 + e2*ga2);
    Mrow[c2] = s*(e0*gb0 + e1*gb1 + e2*gb2);
    if (t == 0) Mrow[AUGCOL] = e0*e0 + e1*e1 + e2*e2 - (double)d0v[c];
}

// ---------------------------------------------------------------------------
// f64 panel factorization with partial pivoting. ONE ROW PER THREAD:
// r[64] doubles = 128 VGPRs (+~50 working) stays under the 256 arch-VGPR cap
// -- the R2 version (2 rows/thread = 256 VGPRs of arrays) spilled everything
// to scratch (VGPR_Count=68, 2.6 GB FETCH per dispatch, ~1 ms each).
// grid (8 b) x 512
__global__ __launch_bounds__(512, 2) void k_panel(float* __restrict__ ws, int kb)
{
    const int b = blockIdx.x, t = threadIdx.x;
    const int m = CC - kb*64, base = kb*64;
    double* M = (double*)(ws + M_OFF) + (size_t)b*CC*MP;

    __shared__ double bufA[64];
    __shared__ double bufB[64];
    __shared__ double wv[8];
    __shared__ int    wi[8];
    __shared__ int    perm[CC];

    const bool h = (t < m);
    double r[64];
    if (h){
        const double* sp = M + (size_t)(base + t)*MP + base;
        #pragma unroll
        for (int j = 0; j < 64; ++j) r[j] = sp[j];
    }
    perm[t] = t;
    __syncthreads();

    #pragma unroll
    for (int k = 0; k < 64; ++k){
        // ---- pivot search on column k (first-max like LAPACK) ----
        const double v = (h && t >= k) ? fabs(r[k]) : -1.0;
        double vmax = v;
        #pragma unroll
        for (int off = 32; off; off >>= 1){
            const double o = __shfl_xor(vmax, off);
            vmax = fmax(vmax, o);
        }
        int idx = (v >= 0.0 && v == vmax) ? t : (1 << 20);
        #pragma unroll
        for (int off = 32; off; off >>= 1){
            const int o = __shfl_xor(idx, off);
            idx = min(idx, o);
        }
        if ((t & 63) == 0){ wv[t>>6] = vmax; wi[t>>6] = idx; }
        __syncthreads();
        double gv = wv[0];
        #pragma unroll
        for (int w = 1; w < 8; ++w) gv = fmax(gv, wv[w]);
        int lb = 1 << 20;
        #pragma unroll
        for (int w = 0; w < 8; ++w) if (wv[w] == gv) lb = min(lb, wi[w]);
        // ---- exchange rows k <-> lb (bufB holds the pivot row) ----
        if (lb != k && t == k){
            #pragma unroll
            for (int j = 0; j < 64; ++j) bufA[j] = r[j];
        }
        if (t == lb){
            #pragma unroll
            for (int j = 0; j < 64; ++j) bufB[j] = r[j];
        }
        if (t == 0 && lb != k){ const int tp = perm[k]; perm[k] = perm[lb]; perm[lb] = tp; }
        __syncthreads();
        if (lb != k){
            if (t == k){
                #pragma unroll
                for (int j = 0; j < 64; ++j) r[j] = bufB[j];
            }
            if (t == lb){
                #pragma unroll
                for (int j = 0; j < 64; ++j) r[j] = bufA[j];
            }
        }
        const double pv = bufB[k];
        // ---- scale + rank-1 update (rows > k) ----
        if (h && t > k){
            const double ml = r[k] / pv; r[k] = ml;
            #pragma unroll
            for (int j = k+1; j < 64; ++j) r[j] = fma(-ml, bufB[j], r[j]);
        }
    }

    if (h){
        double* dp = M + (size_t)(base + t)*MP + base;
        #pragma unroll
        for (int j = 0; j < 64; ++j) dp[j] = r[j];
    }
    int* gp = (int*)(ws + PERM_OFF) + b*CC;
    if (t < m) gp[t] = perm[t];
}

// ---------------------------------------------------------------------------
// Per 32-col stripe: permute U12 rows to LDS + A22 rows to T, then TRSM
// (forward substitution with unit-lower L), write U12 back.
// grid (2*(7-kb)+1 stripes, 8 b) x 256
__global__ __launch_bounds__(256) void k_apply(float* __restrict__ ws, int kb)
{
    const int sx = blockIdx.x, b = blockIdx.y, t = threadIdx.x;
    const int nfull = 2*(7 - kb);
    const bool isaug = (sx == nfull);
    const int cs = isaug ? AUGCOL : (kb+1)*64 + sx*32;
    const int W  = isaug ? 1 : 32;
    const int m = CC - kb*64, base = kb*64;
    double* M = (double*)(ws + M_OFF) + (size_t)b*CC*MP;
    double* T = (double*)(ws + T_OFF) + (size_t)b*CC*MP;
    const int* perm = (const int*)(ws + PERM_OFF) + b*CC;

    __shared__ double LT[64][66];   // LT[s][i] = L[i][s]
    __shared__ double Bs[64][34];

    for (int idx = t; idx < 4096; idx += 256){
        const int i = idx >> 6, s = idx & 63;
        LT[s][i] = M[(size_t)(base+i)*MP + base + s];
    }
    const int c = t & 31, rg = t >> 5;
    for (int i = rg; i < 64; i += 8)
        if (c < W) Bs[i][c] = M[(size_t)(base + perm[i])*MP + cs + c];
    for (int l = 64 + rg; l < m; l += 8)
        if (c < W) T[(size_t)(base+l)*MP + cs + c] = M[(size_t)(base+perm[l])*MP + cs + c];
    __syncthreads();

    for (int s = 0; s < 63; ++s){
        const double bsc = (c < W) ? Bs[s][c] : 0.0;
        #pragma unroll
        for (int i0 = 0; i0 < 8; ++i0){
            const int i = i0*8 + rg;
            if (i > s && c < W) Bs[i][c] = fma(-LT[s][i], bsc, Bs[i][c]);
        }
        __syncthreads();
    }

    for (int i = rg; i < 64; i += 8)
        if (c < W) M[(size_t)(base+i)*MP + cs + c] = Bs[i][c];
}

// ---------------------------------------------------------------------------
// Trailing update: M[rows][stripe] = T[rows][stripe] - L21*U12 (f64, K=2x32)
// grid (7-kb rt, 8-kb sx, 8 b) x 256
__global__ __launch_bounds__(256) void k_gemm(float* __restrict__ ws, int kb)
{
    const int rt = blockIdx.x, sx = blockIdx.y, b = blockIdx.z, t = threadIdx.x;
    const int nfull = 7 - kb;
    const bool isaug = (sx == nfull);
    const int cs = isaug ? AUGCOL : (kb+1+sx)*64;
    const int W  = isaug ? 1 : 64;
    const int base = kb*64;
    const int gr0 = base + 64 + rt*64;
    double* M = (double*)(ws + M_OFF) + (size_t)b*CC*MP;
    double* T = (double*)(ws + T_OFF) + (size_t)b*CC*MP;

    __shared__ double LTc[32][66];  // LTc[kk][r] = L21[gr0+r][base+ch*32+kk]
    __shared__ double Uc [32][66];  // Uc[kk][c]  = U12[base+ch*32+kk][cs+c]

    const int rq = t >> 4, cq = t & 15;
    double acc[4][4] = {};
    for (int ch = 0; ch < 2; ++ch){
        __syncthreads();
        for (int idx = t; idx < 2048; idx += 256){
            const int r = idx >> 5, kk = idx & 31;
            LTc[kk][r] = M[(size_t)(gr0+r)*MP + base + ch*32 + kk];
        }
        for (int idx = t; idx < 2048; idx += 256){
            const int rr2 = idx >> 6, cc2 = idx & 63;
            Uc[rr2][cc2] = (cc2 < W) ? M[(size_t)(base + ch*32 + rr2)*MP + cs + cc2] : 0.0;
        }
        __syncthreads();
        for (int kk = 0; kk < 32; ++kk){
            const double lv0 = LTc[kk][rq*4+0], lv1 = LTc[kk][rq*4+1];
            const double lv2 = LTc[kk][rq*4+2], lv3 = LTc[kk][rq*4+3];
            const double uv0 = Uc[kk][cq*4+0], uv1 = Uc[kk][cq*4+1];
            const double uv2 = Uc[kk][cq*4+2], uv3 = Uc[kk][cq*4+3];
            acc[0][0]=fma(lv0,uv0,acc[0][0]); acc[0][1]=fma(lv0,uv1,acc[0][1]);
            acc[0][2]=fma(lv0,uv2,acc[0][2]); acc[0][3]=fma(lv0,uv3,acc[0][3]);
            acc[1][0]=fma(lv1,uv0,acc[1][0]); acc[1][1]=fma(lv1,uv1,acc[1][1]);
            acc[1][2]=fma(lv1,uv2,acc[1][2]); acc[1][3]=fma(lv1,uv3,acc[1][3]);
            acc[2][0]=fma(lv2,uv0,acc[2][0]); acc[2][1]=fma(lv2,uv1,acc[2][1]);
            acc[2][2]=fma(lv2,uv2,acc[2][2]); acc[2][3]=fma(lv2,uv3,acc[2][3]);
            acc[3][0]=fma(lv3,uv0,acc[3][0]); acc[3][1]=fma(lv3,uv1,acc[3][1]);
            acc[3][2]=fma(lv3,uv2,acc[3][2]); acc[3][3]=fma(lv3,uv3,acc[3][3]);
        }
    }
    #pragma unroll
    for (int i = 0; i < 4; ++i)
        #pragma unroll
        for (int j = 0; j < 4; ++j){
            const int c2 = cq*4 + j;
            if (c2 < W){
                const size_t o = (size_t)(gr0 + rq*4 + i)*MP + cs + c2;
                M[o] = T[o] - acc[i][j];
            }
        }
}

// ---------------------------------------------------------------------------
// Back-substitution on U with eliminated aug column; lmd -= delta. grid (8 b)
__global__ __launch_bounds__(256) void k_backsub(float* __restrict__ ws)
{
    const int b = blockIdx.x, t = threadIdx.x;
    double* M = (double*)(ws + M_OFF) + (size_t)b*CC*MP;
    __shared__ double y[CC];
    __shared__ double Ud[64][65];
    y[t]     = M[(size_t)t*MP + AUGCOL];
    y[t+256] = M[(size_t)(t+256)*MP + AUGCOL];
    __syncthreads();
    for (int sb = 7; sb >= 0; --sb){
        const int rb = sb*64;
        for (int idx = t; idx < 4096; idx += 256)
            Ud[idx>>6][idx&63] = M[(size_t)(rb + (idx>>6))*MP + rb + (idx&63)];
        __syncthreads();
        if (t < 64){
            double yv = y[rb + t];
            for (int kk = 63; kk >= 0; --kk){
                double xk = __shfl(yv, kk);
                xk = xk / Ud[kk][kk];
                if (t == kk) yv = xk;
                else if (t < kk) yv = fma(-Ud[t][kk], xk, yv);
            }
            y[rb + t] = yv;
        }
        __syncthreads();
        for (int r = t; r < rb; r += 256){
            const double* Mr = M + (size_t)r*MP + rb;
            double sacc = 0.0;
            for (int j = 0; j < 64; ++j) sacc = fma(Mr[j], y[rb + j], sacc);
            y[r] -= sacc;
        }
        __syncthreads();
    }
    double* l = (double*)(ws + LMD_OFF) + (size_t)b*CC;
    l[t]     -= y[t];
    l[t+256] -= y[t+256];
}

// ---------------------------------------------------------------------------
// Split-K partial of sum_c lmd*jacp (f64 accum, f32 store).
// grid (24 nb, 8 b, 8 kc) x 256
__global__ void k_frc(const float* __restrict__ jacp, float* __restrict__ ws)
{
    const int nb = blockIdx.x, b = blockIdx.y, kc = blockIdx.z, t = threadIdx.x;
    const int nd = nb*256 + t;
    const double* l = (const double*)(ws + LMD_OFF) + (size_t)b*CC + kc*64;
    const float* J = jacp + ((size_t)(b*CC + kc*64))*NN*3 + nd;
    double acc = 0.0;
    for (int c2 = 0; c2 < 64; ++c2) acc = fma(l[c2], (double)J[(size_t)c2*NN*3], acc);
    ws[PART_OFF + ((size_t)kc*8 + b)*6144 + nd] = (float)acc;
}

// ---------------------------------------------------------------------------
// Combine partials, write pos_new, mom_new, lmd.  grid (208) x 256
__global__ void k_out(const float* __restrict__ pos, const float* __restrict__ mom,
                      const float* __restrict__ mas, const float* __restrict__ dtm,
                      const float* __restrict__ ws, float* __restrict__ out)
{
    const int wg = blockIdx.x, t = threadIdx.x;
    if (wg < 192){
        const int b = wg / 24, nb = wg % 24;
        const int nd = nb*256 + t;
        float sacc = 0.f;
        for (int kc = 0; kc < 8; ++kc) sacc += ws[PART_OFF + ((size_t)kc*8 + b)*6144 + nd];
        const float frc = -sacc;
        const int n = nd / 3;
        const float dt = dtm[b], dt2 = dt*dt;
        out[(size_t)b*6144 + nd]         = pos[(size_t)b*6144 + nd] + frc / mas[b*NN + n] * dt2;
        out[49152 + (size_t)b*6144 + nd] = mom[(size_t)b*6144 + nd] + frc * dt;
    } else {
        const int idx = (wg - 192)*256 + t;      // 0..4095
        out[98304 + idx] = (float)(((const double*)(ws + LMD_OFF))[idx]);
    }
}

// ---------------------------------------------------------------------------
extern "C" void kernel_launch(void* const* d_in, const int* in_sizes, int n_in,
                              void* d_out, int out_size, void* d_ws, size_t ws_size,
                              hipStream_t stream)
{
    (void)in_sizes; (void)n_in; (void)out_size; (void)ws_size;
    const float* pos  = (const float*)d_in[0];
    const float* mom  = (const float*)d_in[1];
    const float* mas  = (const float*)d_in[2];
    const float* dtm  = (const float*)d_in[3];
    const float* jacp = (const float*)d_in[4];
    const int*   pi   = (const int*)d_in[5];
    const int*   pj   = (const int*)d_in[6];
    const float* d0v  = (const float*)d_in[7];
    float* ws  = (float*)d_ws;
    float* out = (float*)d_out;

    k_gbuild<<<dim3(CC, BB), 256, 0, stream>>>(pos, mas, jacp, pi, pj, ws);
    for (int it = 0; it < NITER; ++it){
        k_build<<<dim3(CC, BB), 256, 0, stream>>>(d0v, dtm, ws);
        for (int kb = 0; kb < 8; ++kb){
            k_panel<<<dim3(BB), 512, 0, stream>>>(ws, kb);
            k_apply<<<dim3(2*(7-kb)+1, BB), 256, 0, stream>>>(ws, kb);
            if (kb < 7)
                k_gemm<<<dim3(7-kb, 8-kb, BB), 256, 0, stream>>>(ws, kb);
        }
        k_backsub<<<dim3(BB), 256, 0, stream>>>(ws);
    }
    k_frc<<<dim3(24, BB, 8), 256, 0, stream>>>(jacp, ws);
    k_out<<<dim3(208), 256, 0, stream>>>(pos, mom, mas, dtm, ws, out);
}

// Round 4
// 6090.898 us; speedup vs baseline: 3.5304x; 3.0132x over previous
//
#include <hip/hip_runtime.h>
#include <cmath>

#define BB 8
#define NN 2048
#define CC 512
#define NITER 3
#define MP 516
#define AUGCOL 512

// workspace layout (units: floats); all double regions 8B-aligned (even offsets)
static constexpr size_t G_OFF  = 0;                          // f32 [B][3][C][C]
static constexpr size_t G_SZ   = (size_t)BB*3*CC*CC;         // 6291456
static constexpr size_t M_OFF  = G_OFF + G_SZ;               // f64 [B][C][MP]
static constexpr size_t M_SZF  = (size_t)BB*CC*MP*2;         // 4227072 floats
static constexpr size_t T_OFF  = M_OFF + M_SZF;              // f64 [B][C][MP]
static constexpr size_t DF_OFF = T_OFF + M_SZF;              // f64 [B][C][3]
static constexpr size_t DF_SZF = (size_t)BB*CC*3*2;
static constexpr size_t LMD_OFF= DF_OFF + DF_SZF;            // f64 [B][C]
static constexpr size_t LMD_SZF= (size_t)BB*CC*2;
static constexpr size_t PERM_OFF = LMD_OFF + LMD_SZF;        // int [B][C]
static constexpr size_t PERM_SZ  = (size_t)BB*CC;
static constexpr size_t PART_OFF = PERM_OFF + PERM_SZ;       // f32 [8][B][6144]

// ---------------------------------------------------------------------------
// G[b][d][c][c'] = jacp[b,c',i_c,d]/m_i - jacp[b,c',j_c,d]/m_j (f64 math, f32
// store); diff0 (f64); zero lambda (f64).   grid (512 c, 8 b) x 256
__global__ void k_gbuild(const float* __restrict__ pos, const float* __restrict__ mas,
                         const float* __restrict__ jacp, const int* __restrict__ pi,
                         const int* __restrict__ pj, float* __restrict__ ws)
{
    const int c = blockIdx.x, b = blockIdx.y, t = threadIdx.x;
    const int i = pi[c], j = pj[c];
    const double im = 1.0 / (double)mas[b*NN + i];
    const double jm = 1.0 / (double)mas[b*NN + j];
    float* G = ws + G_OFF;
    const float* Ji = jacp + ((size_t)b*CC*NN + i)*3;
    const float* Jj = jacp + ((size_t)b*CC*NN + j)*3;
    for (int cp = t; cp < CC; cp += 256){
        const size_t o = (size_t)cp*NN*3;
        const size_t gb = ((size_t)(b*3+0)*CC + c)*CC + cp;
        G[gb]                   = (float)((double)Ji[o+0]*im - (double)Jj[o+0]*jm);
        G[gb + (size_t)CC*CC]   = (float)((double)Ji[o+1]*im - (double)Jj[o+1]*jm);
        G[gb + (size_t)2*CC*CC] = (float)((double)Ji[o+2]*im - (double)Jj[o+2]*jm);
    }
    if (t == 0){
        double* df = (double*)(ws + DF_OFF) + ((size_t)b*CC + c)*3;
        for (int d = 0; d < 3; ++d)
            df[d] = (double)pos[((size_t)b*NN+i)*3+d] - (double)pos[((size_t)b*NN+j)*3+d];
    }
    if (c == 0){
        double* l = (double*)(ws + LMD_OFF) + (size_t)b*CC;
        l[t] = 0.0; l[t+256] = 0.0;
    }
}

// ---------------------------------------------------------------------------
// y = G.lmd (f64 accum), dif = diff0 - dt2*y, M[c][c'] = -2dt2*sum_d dif_d*G,
// M[c][512] = |dif|^2 - d0.   grid (512 c, 8 b) x 256
__global__ void k_build(const float* __restrict__ d0v, const float* __restrict__ dtm,
                        float* __restrict__ ws)
{
    const int c = blockIdx.x, b = blockIdx.y, t = threadIdx.x;
    const float* G = ws + G_OFF;
    const double* l = (const double*)(ws + LMD_OFF) + (size_t)b*CC;
    const double dt = (double)dtm[b], dt2 = dt*dt;
    const size_t g0 = ((size_t)(b*3+0)*CC + c)*CC;
    const size_t g1 = g0 + (size_t)CC*CC;
    const size_t g2 = g0 + (size_t)2*CC*CC;
    const int c1 = t, c2 = t + 256;
    const double l1 = l[c1], l2 = l[c2];
    const double ga0 = (double)G[g0+c1], gb0 = (double)G[g0+c2];
    const double ga1 = (double)G[g1+c1], gb1 = (double)G[g1+c2];
    const double ga2 = (double)G[g2+c1], gb2 = (double)G[g2+c2];
    double p0 = ga0*l1 + gb0*l2;
    double p1 = ga1*l1 + gb1*l2;
    double p2 = ga2*l1 + gb2*l2;
    __shared__ double red[12];
    #pragma unroll
    for (int off = 32; off; off >>= 1){
        p0 += __shfl_xor(p0, off);
        p1 += __shfl_xor(p1, off);
        p2 += __shfl_xor(p2, off);
    }
    if ((t & 63) == 0){ const int w = t>>6; red[w*3+0]=p0; red[w*3+1]=p1; red[w*3+2]=p2; }
    __syncthreads();
    const double y0 = red[0]+red[3]+red[6]+red[9];
    const double y1 = red[1]+red[4]+red[7]+red[10];
    const double y2 = red[2]+red[5]+red[8]+red[11];
    const double* df = (const double*)(ws + DF_OFF) + ((size_t)b*CC + c)*3;
    const double e0 = df[0] - dt2*y0;
    const double e1 = df[1] - dt2*y1;
    const double e2 = df[2] - dt2*y2;
    const double s = -2.0*dt2;
    double* Mrow = (double*)(ws + M_OFF) + ((size_t)b*CC + c)*MP;
    Mrow[c1] = s*(e0*ga0 + e1*ga1 + e2*ga2);
    Mrow[c2] = s*(e0*gb0 + e1*gb1 + e2*gb2);
    if (t == 0) Mrow[AUGCOL] = e0*e0 + e1*e1 + e2*e2 - (double)d0v[c];
}

// ---------------------------------------------------------------------------
// Wave-uniform-index read of a register array: k lives in an SGPR, so the
// switch compiles to a scalar jump table (a few s-ops + one v_mov pair per
// case) and -- critically -- never makes r[] addressable, so it stays in
// VGPRs. Dynamic indexing (r[k] in a rolled loop) put the whole array in
// scratch in R2/R3: VGPR_Count=64, 2.7 GB FETCH/dispatch, 800 us/panel.
__device__ __forceinline__ double sel64(const double (&r)[64], int k)
{
    double v;
    switch (k){
#define C1(i) case i: v = r[i]; break;
#define C8(i) C1(i) C1((i)+1) C1((i)+2) C1((i)+3) C1((i)+4) C1((i)+5) C1((i)+6) C1((i)+7)
        C8(0) C8(8) C8(16) C8(24) C8(32) C8(40) C8(48) C8(56)
#undef C8
#undef C1
        default: v = 0.0; break;
    }
    return v;
}

// ---------------------------------------------------------------------------
// f64 panel factorization with partial pivoting, one row per thread, rolled
// k-loop, all register-array indices static. The masked pivot row bufBm
// (0 below k, pv-1 at k, row above k) lets the update be a full static
// 64-wide FMA; the j==k lane turns r[k] into the multiplier as a byproduct.
// grid (8 b) x 512
__global__ __launch_bounds__(512, 2) void k_panel(float* __restrict__ ws, int kb)
{
    const int b = blockIdx.x, t = threadIdx.x;
    const int m = CC - kb*64, base = kb*64;
    double* M = (double*)(ws + M_OFF) + (size_t)b*CC*MP;

    __shared__ double bufA[64];
    __shared__ double bufB[64];
    __shared__ double bufBm[64];
    __shared__ double wv[8];
    __shared__ int    wi[8];
    __shared__ int    perm[CC];

    const bool h = (t < m);
    double r[64];
    if (h){
        const double* sp = M + (size_t)(base + t)*MP + base;
        #pragma unroll
        for (int j = 0; j < 64; ++j) r[j] = sp[j];
    }
    perm[t] = t;
    __syncthreads();

    for (int k = 0; k < 64; ++k){            // intentionally rolled
        const double rk_pre = sel64(r, k);
        // ---- pivot search on column k (first-max like LAPACK) ----
        const double v = (h && t >= k) ? fabs(rk_pre) : -1.0;
        double vmax = v;
        #pragma unroll
        for (int off = 32; off; off >>= 1){
            const double o = __shfl_xor(vmax, off);
            vmax = fmax(vmax, o);
        }
        int idx = (v >= 0.0 && v == vmax) ? t : (1 << 20);
        #pragma unroll
        for (int off = 32; off; off >>= 1){
            const int o = __shfl_xor(idx, off);
            idx = min(idx, o);
        }
        if ((t & 63) == 0){ wv[t>>6] = vmax; wi[t>>6] = idx; }
        __syncthreads();                     // B1
        double gv = wv[0];
        #pragma unroll
        for (int w = 1; w < 8; ++w) gv = fmax(gv, wv[w]);
        int lb = 1 << 20;
        #pragma unroll
        for (int w = 0; w < 8; ++w) if (wv[w] == gv) lb = min(lb, wi[w]);
        // ---- stage rows k (bufA) and lb (bufB) in LDS ----
        if (lb != k && t == k){
            #pragma unroll
            for (int j = 0; j < 64; ++j) bufA[j] = r[j];
        }
        if (t == lb){
            #pragma unroll
            for (int j = 0; j < 64; ++j) bufB[j] = r[j];
        }
        if (t == 0 && lb != k){ const int tp = perm[k]; perm[k] = perm[lb]; perm[lb] = tp; }
        __syncthreads();                     // B2
        double rk = rk_pre;
        if (lb != k){
            if (t == k){
                #pragma unroll
                for (int j = 0; j < 64; ++j) r[j] = bufB[j];
            }
            if (t == lb){
                #pragma unroll
                for (int j = 0; j < 64; ++j) r[j] = bufA[j];
                rk = bufA[k];                // dynamic LDS index: fine
            }
        }
        const double pv = bufB[k];
        if (t < 64) bufBm[t] = (t < k) ? 0.0 : (t == k ? pv - 1.0 : bufB[t]);
        __syncthreads();                     // B3
        // ---- masked full-width rank-1 update (rows > k) ----
        if (h && t > k){
            const double ml = rk / pv;
            #pragma unroll
            for (int j = 0; j < 64; ++j) r[j] = fma(-ml, bufBm[j], r[j]);
        }
    }

    if (h){
        double* dp = M + (size_t)(base + t)*MP + base;
        #pragma unroll
        for (int j = 0; j < 64; ++j) dp[j] = r[j];
    }
    int* gp = (int*)(ws + PERM_OFF) + b*CC;
    if (t < m) gp[t] = perm[t];
}

// ---------------------------------------------------------------------------
// Per 32-col stripe: permute U12 rows to LDS + A22 rows to T, then TRSM
// (forward substitution with unit-lower L), write U12 back.
// grid (2*(7-kb)+1 stripes, 8 b) x 256
__global__ __launch_bounds__(256) void k_apply(float* __restrict__ ws, int kb)
{
    const int sx = blockIdx.x, b = blockIdx.y, t = threadIdx.x;
    const int nfull = 2*(7 - kb);
    const bool isaug = (sx == nfull);
    const int cs = isaug ? AUGCOL : (kb+1)*64 + sx*32;
    const int W  = isaug ? 1 : 32;
    const int m = CC - kb*64, base = kb*64;
    double* M = (double*)(ws + M_OFF) + (size_t)b*CC*MP;
    double* T = (double*)(ws + T_OFF) + (size_t)b*CC*MP;
    const int* perm = (const int*)(ws + PERM_OFF) + b*CC;

    __shared__ double LT[64][66];   // LT[s][i] = L[i][s]
    __shared__ double Bs[64][34];

    for (int idx = t; idx < 4096; idx += 256){
        const int i = idx >> 6, s = idx & 63;
        LT[s][i] = M[(size_t)(base+i)*MP + base + s];
    }
    const int c = t & 31, rg = t >> 5;
    for (int i = rg; i < 64; i += 8)
        if (c < W) Bs[i][c] = M[(size_t)(base + perm[i])*MP + cs + c];
    for (int l = 64 + rg; l < m; l += 8)
        if (c < W) T[(size_t)(base+l)*MP + cs + c] = M[(size_t)(base+perm[l])*MP + cs + c];
    __syncthreads();

    for (int s = 0; s < 63; ++s){
        const double bsc = (c < W) ? Bs[s][c] : 0.0;
        #pragma unroll
        for (int i0 = 0; i0 < 8; ++i0){
            const int i = i0*8 + rg;
            if (i > s && c < W) Bs[i][c] = fma(-LT[s][i], bsc, Bs[i][c]);
        }
        __syncthreads();
    }

    for (int i = rg; i < 64; i += 8)
        if (c < W) M[(size_t)(base+i)*MP + cs + c] = Bs[i][c];
}

// ---------------------------------------------------------------------------
// Trailing update: M[rows][stripe] = T[rows][stripe] - L21*U12 (f64, K=2x32)
// grid (7-kb rt, 8-kb sx, 8 b) x 256
__global__ __launch_bounds__(256) void k_gemm(float* __restrict__ ws, int kb)
{
    const int rt = blockIdx.x, sx = blockIdx.y, b = blockIdx.z, t = threadIdx.x;
    const int nfull = 7 - kb;
    const bool isaug = (sx == nfull);
    const int cs = isaug ? AUGCOL : (kb+1+sx)*64;
    const int W  = isaug ? 1 : 64;
    const int base = kb*64;
    const int gr0 = base + 64 + rt*64;
    double* M = (double*)(ws + M_OFF) + (size_t)b*CC*MP;
    double* T = (double*)(ws + T_OFF) + (size_t)b*CC*MP;

    __shared__ double LTc[32][66];  // LTc[kk][r] = L21[gr0+r][base+ch*32+kk]
    __shared__ double Uc [32][66];  // Uc[kk][c]  = U12[base+ch*32+kk][cs+c]

    const int rq = t >> 4, cq = t & 15;
    double acc[4][4] = {};
    for (int ch = 0; ch < 2; ++ch){
        __syncthreads();
        for (int idx = t; idx < 2048; idx += 256){
            const int r = idx >> 5, kk = idx & 31;
            LTc[kk][r] = M[(size_t)(gr0+r)*MP + base + ch*32 + kk];
        }
        for (int idx = t; idx < 2048; idx += 256){
            const int rr2 = idx >> 6, cc2 = idx & 63;
            Uc[rr2][cc2] = (cc2 < W) ? M[(size_t)(base + ch*32 + rr2)*MP + cs + cc2] : 0.0;
        }
        __syncthreads();
        for (int kk = 0; kk < 32; ++kk){
            const double lv0 = LTc[kk][rq*4+0], lv1 = LTc[kk][rq*4+1];
            const double lv2 = LTc[kk][rq*4+2], lv3 = LTc[kk][rq*4+3];
            const double uv0 = Uc[kk][cq*4+0], uv1 = Uc[kk][cq*4+1];
            const double uv2 = Uc[kk][cq*4+2], uv3 = Uc[kk][cq*4+3];
            acc[0][0]=fma(lv0,uv0,acc[0][0]); acc[0][1]=fma(lv0,uv1,acc[0][1]);
            acc[0][2]=fma(lv0,uv2,acc[0][2]); acc[0][3]=fma(lv0,uv3,acc[0][3]);
            acc[1][0]=fma(lv1,uv0,acc[1][0]); acc[1][1]=fma(lv1,uv1,acc[1][1]);
            acc[1][2]=fma(lv1,uv2,acc[1][2]); acc[1][3]=fma(lv1,uv3,acc[1][3]);
            acc[2][0]=fma(lv2,uv0,acc[2][0]); acc[2][1]=fma(lv2,uv1,acc[2][1]);
            acc[2][2]=fma(lv2,uv2,acc[2][2]); acc[2][3]=fma(lv2,uv3,acc[2][3]);
            acc[3][0]=fma(lv3,uv0,acc[3][0]); acc[3][1]=fma(lv3,uv1,acc[3][1]);
            acc[3][2]=fma(lv3,uv2,acc[3][2]); acc[3][3]=fma(lv3,uv3,acc[3][3]);
        }
    }
    #pragma unroll
    for (int i = 0; i < 4; ++i)
        #pragma unroll
        for (int j = 0; j < 4; ++j){
            const int c2 = cq*4 + j;
            if (c2 < W){
                const size_t o = (size_t)(gr0 + rq*4 + i)*MP + cs + c2;
                M[o] = T[o] - acc[i][j];
            }
        }
}

// ---------------------------------------------------------------------------
// Back-substitution on U with eliminated aug column; lmd -= delta. grid (8 b)
__global__ __launch_bounds__(256) void k_backsub(float* __restrict__ ws)
{
    const int b = blockIdx.x, t = threadIdx.x;
    double* M = (double*)(ws + M_OFF) + (size_t)b*CC*MP;
    __shared__ double y[CC];
    __shared__ double Ud[64][65];
    y[t]     = M[(size_t)t*MP + AUGCOL];
    y[t+256] = M[(size_t)(t+256)*MP + AUGCOL];
    __syncthreads();
    for (int sb = 7; sb >= 0; --sb){
        const int rb = sb*64;
        for (int idx = t; idx < 4096; idx += 256)
            Ud[idx>>6][idx&63] = M[(size_t)(rb + (idx>>6))*MP + rb + (idx&63)];
        __syncthreads();
        if (t < 64){
            double yv = y[rb + t];
            for (int kk = 63; kk >= 0; --kk){
                double xk = __shfl(yv, kk);
                xk = xk / Ud[kk][kk];
                if (t == kk) yv = xk;
                else if (t < kk) yv = fma(-Ud[t][kk], xk, yv);
            }
            y[rb + t] = yv;
        }
        __syncthreads();
        for (int r = t; r < rb; r += 256){
            const double* Mr = M + (size_t)r*MP + rb;
            double sacc = 0.0;
            for (int j = 0; j < 64; ++j) sacc = fma(Mr[j], y[rb + j], sacc);
            y[r] -= sacc;
        }
        __syncthreads();
    }
    double* l = (double*)(ws + LMD_OFF) + (size_t)b*CC;
    l[t]     -= y[t];
    l[t+256] -= y[t+256];
}

// ---------------------------------------------------------------------------
// Split-K partial of sum_c lmd*jacp (f64 accum, f32 store).
// grid (24 nb, 8 b, 8 kc) x 256
__global__ void k_frc(const float* __restrict__ jacp, float* __restrict__ ws)
{
    const int nb = blockIdx.x, b = blockIdx.y, kc = blockIdx.z, t = threadIdx.x;
    const int nd = nb*256 + t;
    const double* l = (const double*)(ws + LMD_OFF) + (size_t)b*CC + kc*64;
    const float* J = jacp + ((size_t)(b*CC + kc*64))*NN*3 + nd;
    double acc = 0.0;
    for (int c2 = 0; c2 < 64; ++c2) acc = fma(l[c2], (double)J[(size_t)c2*NN*3], acc);
    ws[PART_OFF + ((size_t)kc*8 + b)*6144 + nd] = (float)acc;
}

// ---------------------------------------------------------------------------
// Combine partials, write pos_new, mom_new, lmd.  grid (208) x 256
__global__ void k_out(const float* __restrict__ pos, const float* __restrict__ mom,
                      const float* __restrict__ mas, const float* __restrict__ dtm,
                      const float* __restrict__ ws, float* __restrict__ out)
{
    const int wg = blockIdx.x, t = threadIdx.x;
    if (wg < 192){
        const int b = wg / 24, nb = wg % 24;
        const int nd = nb*256 + t;
        float sacc = 0.f;
        for (int kc = 0; kc < 8; ++kc) sacc += ws[PART_OFF + ((size_t)kc*8 + b)*6144 + nd];
        const float frc = -sacc;
        const int n = nd / 3;
        const float dt = dtm[b], dt2 = dt*dt;
        out[(size_t)b*6144 + nd]         = pos[(size_t)b*6144 + nd] + frc / mas[b*NN + n] * dt2;
        out[49152 + (size_t)b*6144 + nd] = mom[(size_t)b*6144 + nd] + frc * dt;
    } else {
        const int idx = (wg - 192)*256 + t;      // 0..4095
        out[98304 + idx] = (float)(((const double*)(ws + LMD_OFF))[idx]);
    }
}

// ---------------------------------------------------------------------------
extern "C" void kernel_launch(void* const* d_in, const int* in_sizes, int n_in,
                              void* d_out, int out_size, void* d_ws, size_t ws_size,
                              hipStream_t stream)
{
    (void)in_sizes; (void)n_in; (void)out_size; (void)ws_size;
    const float* pos  = (const float*)d_in[0];
    const float* mom  = (const float*)d_in[1];
    const float* mas  = (const float*)d_in[2];
    const float* dtm  = (const float*)d_in[3];
    const float* jacp = (const float*)d_in[4];
    const int*   pi   = (const int*)d_in[5];
    const int*   pj   = (const int*)d_in[6];
    const float* d0v  = (const float*)d_in[7];
    float* ws  = (float*)d_ws;
    float* out = (float*)d_out;

    k_gbuild<<<dim3(CC, BB), 256, 0, stream>>>(pos, mas, jacp, pi, pj, ws);
    for (int it = 0; it < NITER; ++it){
        k_build<<<dim3(CC, BB), 256, 0, stream>>>(d0v, dtm, ws);
        for (int kb = 0; kb < 8; ++kb){
            k_panel<<<dim3(BB), 512, 0, stream>>>(ws, kb);
            k_apply<<<dim3(2*(7-kb)+1, BB), 256, 0, stream>>>(ws, kb);
            if (kb < 7)
                k_gemm<<<dim3(7-kb, 8-kb, BB), 256, 0, stream>>>(ws, kb);
        }
        k_backsub<<<dim3(BB), 256, 0, stream>>>(ws);
    }
    k_frc<<<dim3(24, BB, 8), 256, 0, stream>>>(jacp, ws);
    k_out<<<dim3(208), 256, 0, stream>>>(pos, mom, mas, dtm, ws, out);
}

// Round 5
// 5845.341 us; speedup vs baseline: 3.6787x; 1.0420x over previous
//
#include <hip/hip_runtime.h>
#include <cmath>

#define BB 8
#define NN 2048
#define CC 512
#define NITER 3
#define MP 516
#define AUGCOL 512

// workspace layout (units: floats); all double regions 8B-aligned (even offsets)
static constexpr size_t G_OFF  = 0;                          // f32 [B][3][C][C]
static constexpr size_t G_SZ   = (size_t)BB*3*CC*CC;         // 6291456
static constexpr size_t M_OFF  = G_OFF + G_SZ;               // f64 [B][C][MP]
static constexpr size_t M_SZF  = (size_t)BB*CC*MP*2;         // 4227072 floats
static constexpr size_t T_OFF  = M_OFF + M_SZF;              // f64 [B][C][MP]
static constexpr size_t DF_OFF = T_OFF + M_SZF;              // f64 [B][C][3]
static constexpr size_t DF_SZF = (size_t)BB*CC*3*2;
static constexpr size_t LMD_OFF= DF_OFF + DF_SZF;            // f64 [B][C]
static constexpr size_t LMD_SZF= (size_t)BB*CC*2;
static constexpr size_t PERM_OFF = LMD_OFF + LMD_SZF;        // int [B][C]
static constexpr size_t PERM_SZ  = (size_t)BB*CC;
static constexpr size_t PART_OFF = PERM_OFF + PERM_SZ;       // f32 [8][B][6144]

// ---------------------------------------------------------------------------
// G[b][d][c][c'] = jacp[b,c',i_c,d]/m_i - jacp[b,c',j_c,d]/m_j (f64 math, f32
// store); diff0 (f64); zero lambda (f64).   grid (512 c, 8 b) x 256
__global__ void k_gbuild(const float* __restrict__ pos, const float* __restrict__ mas,
                         const float* __restrict__ jacp, const int* __restrict__ pi,
                         const int* __restrict__ pj, float* __restrict__ ws)
{
    const int c = blockIdx.x, b = blockIdx.y, t = threadIdx.x;
    const int i = pi[c], j = pj[c];
    const double im = 1.0 / (double)mas[b*NN + i];
    const double jm = 1.0 / (double)mas[b*NN + j];
    float* G = ws + G_OFF;
    const float* Ji = jacp + ((size_t)b*CC*NN + i)*3;
    const float* Jj = jacp + ((size_t)b*CC*NN + j)*3;
    for (int cp = t; cp < CC; cp += 256){
        const size_t o = (size_t)cp*NN*3;
        const size_t gb = ((size_t)(b*3+0)*CC + c)*CC + cp;
        G[gb]                   = (float)((double)Ji[o+0]*im - (double)Jj[o+0]*jm);
        G[gb + (size_t)CC*CC]   = (float)((double)Ji[o+1]*im - (double)Jj[o+1]*jm);
        G[gb + (size_t)2*CC*CC] = (float)((double)Ji[o+2]*im - (double)Jj[o+2]*jm);
    }
    if (t == 0){
        double* df = (double*)(ws + DF_OFF) + ((size_t)b*CC + c)*3;
        for (int d = 0; d < 3; ++d)
            df[d] = (double)pos[((size_t)b*NN+i)*3+d] - (double)pos[((size_t)b*NN+j)*3+d];
    }
    if (c == 0){
        double* l = (double*)(ws + LMD_OFF) + (size_t)b*CC;
        l[t] = 0.0; l[t+256] = 0.0;
    }
}

// ---------------------------------------------------------------------------
// y = G.lmd (f64 accum), dif = diff0 - dt2*y, M[c][c'] = -2dt2*sum_d dif_d*G,
// M[c][512] = |dif|^2 - d0.   grid (512 c, 8 b) x 256
__global__ void k_build(const float* __restrict__ d0v, const float* __restrict__ dtm,
                        float* __restrict__ ws)
{
    const int c = blockIdx.x, b = blockIdx.y, t = threadIdx.x;
    const float* G = ws + G_OFF;
    const double* l = (const double*)(ws + LMD_OFF) + (size_t)b*CC;
    const double dt = (double)dtm[b], dt2 = dt*dt;
    const size_t g0 = ((size_t)(b*3+0)*CC + c)*CC;
    const size_t g1 = g0 + (size_t)CC*CC;
    const size_t g2 = g0 + (size_t)2*CC*CC;
    const int c1 = t, c2 = t + 256;
    const double l1 = l[c1], l2 = l[c2];
    const double ga0 = (double)G[g0+c1], gb0 = (double)G[g0+c2];
    const double ga1 = (double)G[g1+c1], gb1 = (double)G[g1+c2];
    const double ga2 = (double)G[g2+c1], gb2 = (double)G[g2+c2];
    double p0 = ga0*l1 + gb0*l2;
    double p1 = ga1*l1 + gb1*l2;
    double p2 = ga2*l1 + gb2*l2;
    __shared__ double red[12];
    #pragma unroll
    for (int off = 32; off; off >>= 1){
        p0 += __shfl_xor(p0, off);
        p1 += __shfl_xor(p1, off);
        p2 += __shfl_xor(p2, off);
    }
    if ((t & 63) == 0){ const int w = t>>6; red[w*3+0]=p0; red[w*3+1]=p1; red[w*3+2]=p2; }
    __syncthreads();
    const double y0 = red[0]+red[3]+red[6]+red[9];
    const double y1 = red[1]+red[4]+red[7]+red[10];
    const double y2 = red[2]+red[5]+red[8]+red[11];
    const double* df = (const double*)(ws + DF_OFF) + ((size_t)b*CC + c)*3;
    const double e0 = df[0] - dt2*y0;
    const double e1 = df[1] - dt2*y1;
    const double e2 = df[2] - dt2*y2;
    const double s = -2.0*dt2;
    double* Mrow = (double*)(ws + M_OFF) + ((size_t)b*CC + c)*MP;
    Mrow[c1] = s*(e0*ga0 + e1*ga1 + e2*ga2);
    Mrow[c2] = s*(e0*gb0 + e1*gb1 + e2*gb2);
    if (t == 0) Mrow[AUGCOL] = e0*e0 + e1*e1 + e2*e2 - (double)d0v[c];
}

// ---------------------------------------------------------------------------
// One pivoted-elimination step, K compile-time. Template recursion forces a
// full unroll with every r[] index STATIC (R3/R4 post-mortems: any rolled
// loop around r[] spilled the array to scratch -> 800/169 us panels).
// Logical row swap: rows never move between threads; each thread tracks its
// logical position `mypos`. 2 barriers per step.
template<int K>
__device__ __forceinline__ void panel_step(double (&r)[64], int& mypos, const bool h,
                                           const int t, double* __restrict__ bufB,
                                           double* __restrict__ wv, int* __restrict__ wi,
                                           int* __restrict__ sh_lw)
{
    // ---- pivot search on column K over threads with mypos >= K ----
    const double v = (h && mypos >= K) ? fabs(r[K]) : -1.0;
    double vmax = v;
    #pragma unroll
    for (int off = 32; off; off >>= 1){
        const double o = __shfl_xor(vmax, off);
        vmax = fmax(vmax, o);
    }
    int idx = (v >= 0.0 && v == vmax) ? t : (1 << 20);
    #pragma unroll
    for (int off = 32; off; off >>= 1){
        const int o = __shfl_xor(idx, off);
        idx = min(idx, o);
    }
    if ((t & 63) == 0){ wv[t>>6] = vmax; wi[t>>6] = idx; }
    __syncthreads();                                   // B1
    double gv = wv[0];
    #pragma unroll
    for (int w = 1; w < 8; ++w) gv = fmax(gv, wv[w]);
    int wp = 1 << 20;
    #pragma unroll
    for (int w = 0; w < 8; ++w) if (wv[w] == gv) wp = min(wp, wi[w]);
    // ---- winner stages pivot row tail; publish its old logical position ----
    if (t == wp){
        *sh_lw = mypos;
        #pragma unroll
        for (int j = K; j < 64; ++j) bufB[j] = r[j];
    }
    __syncthreads();                                   // B2
    const int lw = *sh_lw;
    if (t == wp) mypos = K;
    else if (mypos == K) mypos = lw;
    // ---- scale + rank-1 update (logical rows > K) ----
    if (h && mypos > K){
        const double pv = bufB[K];
        const double ml = r[K] / pv;
        r[K] = ml;
        #pragma unroll
        for (int j = K + 1; j < 64; ++j) r[j] = fma(-ml, bufB[j], r[j]);
    }
}

template<int K>
__device__ __forceinline__ void panel_rec(double (&r)[64], int& mypos, const bool h,
                                          const int t, double* __restrict__ bufB,
                                          double* __restrict__ wv, int* __restrict__ wi,
                                          int* __restrict__ sh_lw)
{
    if constexpr (K < 64){
        panel_step<K>(r, mypos, h, t, bufB, wv, wi, sh_lw);
        panel_rec<K + 1>(r, mypos, h, t, bufB, wv, wi, sh_lw);
    }
}

// ---------------------------------------------------------------------------
// f64 panel factorization with partial pivoting, one row per thread, fully
// unrolled (template recursion), logical row swaps. Writes back rows in
// pivoted order (scatter to M[base+mypos]) and perm[mypos]=t.
// grid (8 b) x 512
__global__ __launch_bounds__(512, 2) void k_panel(float* __restrict__ ws, int kb)
{
    const int b = blockIdx.x, t = threadIdx.x;
    const int m = CC - kb*64, base = kb*64;
    double* M = (double*)(ws + M_OFF) + (size_t)b*CC*MP;

    __shared__ double bufB[64];
    __shared__ double wv[8];
    __shared__ int    wi[8];
    __shared__ int    sh_lw;

    const bool h = (t < m);
    double r[64];
    if (h){
        const double* sp = M + (size_t)(base + t)*MP + base;
        #pragma unroll
        for (int j = 0; j < 64; ++j) r[j] = sp[j];
    }
    int mypos = t;
    __syncthreads();

    panel_rec<0>(r, mypos, h, t, bufB, wv, wi, &sh_lw);

    if (h){
        double* dp = M + (size_t)(base + mypos)*MP + base;
        #pragma unroll
        for (int j = 0; j < 64; ++j) dp[j] = r[j];
        ((int*)(ws + PERM_OFF))[b*CC + mypos] = t;
    }
}

// ---------------------------------------------------------------------------
// Per 32-col stripe: permute U12 rows to LDS + A22 rows to T, then TRSM
// (forward substitution with unit-lower L), write U12 back.
// grid (2*(7-kb)+1 stripes, 8 b) x 256
__global__ __launch_bounds__(256) void k_apply(float* __restrict__ ws, int kb)
{
    const int sx = blockIdx.x, b = blockIdx.y, t = threadIdx.x;
    const int nfull = 2*(7 - kb);
    const bool isaug = (sx == nfull);
    const int cs = isaug ? AUGCOL : (kb+1)*64 + sx*32;
    const int W  = isaug ? 1 : 32;
    const int m = CC - kb*64, base = kb*64;
    double* M = (double*)(ws + M_OFF) + (size_t)b*CC*MP;
    double* T = (double*)(ws + T_OFF) + (size_t)b*CC*MP;
    const int* perm = (const int*)(ws + PERM_OFF) + b*CC;

    __shared__ double LT[64][66];   // LT[s][i] = L[i][s]
    __shared__ double Bs[64][34];

    for (int idx = t; idx < 4096; idx += 256){
        const int i = idx >> 6, s = idx & 63;
        LT[s][i] = M[(size_t)(base+i)*MP + base + s];
    }
    const int c = t & 31, rg = t >> 5;
    for (int i = rg; i < 64; i += 8)
        if (c < W) Bs[i][c] = M[(size_t)(base + perm[i])*MP + cs + c];
    for (int l = 64 + rg; l < m; l += 8)
        if (c < W) T[(size_t)(base+l)*MP + cs + c] = M[(size_t)(base+perm[l])*MP + cs + c];
    __syncthreads();

    for (int s = 0; s < 63; ++s){
        const double bsc = (c < W) ? Bs[s][c] : 0.0;
        #pragma unroll
        for (int i0 = 0; i0 < 8; ++i0){
            const int i = i0*8 + rg;
            if (i > s && c < W) Bs[i][c] = fma(-LT[s][i], bsc, Bs[i][c]);
        }
        __syncthreads();
    }

    for (int i = rg; i < 64; i += 8)
        if (c < W) M[(size_t)(base+i)*MP + cs + c] = Bs[i][c];
}

// ---------------------------------------------------------------------------
// Trailing update: M[rows][stripe] = T[rows][stripe] - L21*U12 (f64, K=2x32)
// grid (7-kb rt, 8-kb sx, 8 b) x 256
__global__ __launch_bounds__(256) void k_gemm(float* __restrict__ ws, int kb)
{
    const int rt = blockIdx.x, sx = blockIdx.y, b = blockIdx.z, t = threadIdx.x;
    const int nfull = 7 - kb;
    const bool isaug = (sx == nfull);
    const int cs = isaug ? AUGCOL : (kb+1+sx)*64;
    const int W  = isaug ? 1 : 64;
    const int base = kb*64;
    const int gr0 = base + 64 + rt*64;
    double* M = (double*)(ws + M_OFF) + (size_t)b*CC*MP;
    double* T = (double*)(ws + T_OFF) + (size_t)b*CC*MP;

    __shared__ double LTc[32][66];  // LTc[kk][r] = L21[gr0+r][base+ch*32+kk]
    __shared__ double Uc [32][66];  // Uc[kk][c]  = U12[base+ch*32+kk][cs+c]

    const int rq = t >> 4, cq = t & 15;
    double acc[4][4] = {};
    for (int ch = 0; ch < 2; ++ch){
        __syncthreads();
        for (int idx = t; idx < 2048; idx += 256){
            const int r = idx >> 5, kk = idx & 31;
            LTc[kk][r] = M[(size_t)(gr0+r)*MP + base + ch*32 + kk];
        }
        for (int idx = t; idx < 2048; idx += 256){
            const int rr2 = idx >> 6, cc2 = idx & 63;
            Uc[rr2][cc2] = (cc2 < W) ? M[(size_t)(base + ch*32 + rr2)*MP + cs + cc2] : 0.0;
        }
        __syncthreads();
        for (int kk = 0; kk < 32; ++kk){
            const double lv0 = LTc[kk][rq*4+0], lv1 = LTc[kk][rq*4+1];
            const double lv2 = LTc[kk][rq*4+2], lv3 = LTc[kk][rq*4+3];
            const double uv0 = Uc[kk][cq*4+0], uv1 = Uc[kk][cq*4+1];
            const double uv2 = Uc[kk][cq*4+2], uv3 = Uc[kk][cq*4+3];
            acc[0][0]=fma(lv0,uv0,acc[0][0]); acc[0][1]=fma(lv0,uv1,acc[0][1]);
            acc[0][2]=fma(lv0,uv2,acc[0][2]); acc[0][3]=fma(lv0,uv3,acc[0][3]);
            acc[1][0]=fma(lv1,uv0,acc[1][0]); acc[1][1]=fma(lv1,uv1,acc[1][1]);
            acc[1][2]=fma(lv1,uv2,acc[1][2]); acc[1][3]=fma(lv1,uv3,acc[1][3]);
            acc[2][0]=fma(lv2,uv0,acc[2][0]); acc[2][1]=fma(lv2,uv1,acc[2][1]);
            acc[2][2]=fma(lv2,uv2,acc[2][2]); acc[2][3]=fma(lv2,uv3,acc[2][3]);
            acc[3][0]=fma(lv3,uv0,acc[3][0]); acc[3][1]=fma(lv3,uv1,acc[3][1]);
            acc[3][2]=fma(lv3,uv2,acc[3][2]); acc[3][3]=fma(lv3,uv3,acc[3][3]);
        }
    }
    #pragma unroll
    for (int i = 0; i < 4; ++i)
        #pragma unroll
        for (int j = 0; j < 4; ++j){
            const int c2 = cq*4 + j;
            if (c2 < W){
                const size_t o = (size_t)(gr0 + rq*4 + i)*MP + cs + c2;
                M[o] = T[o] - acc[i][j];
            }
        }
}

// ---------------------------------------------------------------------------
// Back-substitution on U with eliminated aug column; lmd -= delta. grid (8 b)
__global__ __launch_bounds__(256) void k_backsub(float* __restrict__ ws)
{
    const int b = blockIdx.x, t = threadIdx.x;
    double* M = (double*)(ws + M_OFF) + (size_t)b*CC*MP;
    __shared__ double y[CC];
    __shared__ double Ud[64][65];
    y[t]     = M[(size_t)t*MP + AUGCOL];
    y[t+256] = M[(size_t)(t+256)*MP + AUGCOL];
    __syncthreads();
    for (int sb = 7; sb >= 0; --sb){
        const int rb = sb*64;
        for (int idx = t; idx < 4096; idx += 256)
            Ud[idx>>6][idx&63] = M[(size_t)(rb + (idx>>6))*MP + rb + (idx&63)];
        __syncthreads();
        if (t < 64){
            double yv = y[rb + t];
            for (int kk = 63; kk >= 0; --kk){
                double xk = __shfl(yv, kk);
                xk = xk / Ud[kk][kk];
                if (t == kk) yv = xk;
                else if (t < kk) yv = fma(-Ud[t][kk], xk, yv);
            }
            y[rb + t] = yv;
        }
        __syncthreads();
        for (int r = t; r < rb; r += 256){
            const double* Mr = M + (size_t)r*MP + rb;
            double sacc = 0.0;
            for (int j = 0; j < 64; ++j) sacc = fma(Mr[j], y[rb + j], sacc);
            y[r] -= sacc;
        }
        __syncthreads();
    }
    double* l = (double*)(ws + LMD_OFF) + (size_t)b*CC;
    l[t]     -= y[t];
    l[t+256] -= y[t+256];
}

// ---------------------------------------------------------------------------
// Split-K partial of sum_c lmd*jacp (f64 accum, f32 store).
// grid (24 nb, 8 b, 8 kc) x 256
__global__ void k_frc(const float* __restrict__ jacp, float* __restrict__ ws)
{
    const int nb = blockIdx.x, b = blockIdx.y, kc = blockIdx.z, t = threadIdx.x;
    const int nd = nb*256 + t;
    const double* l = (const double*)(ws + LMD_OFF) + (size_t)b*CC + kc*64;
    const float* J = jacp + ((size_t)(b*CC + kc*64))*NN*3 + nd;
    double acc = 0.0;
    for (int c2 = 0; c2 < 64; ++c2) acc = fma(l[c2], (double)J[(size_t)c2*NN*3], acc);
    ws[PART_OFF + ((size_t)kc*8 + b)*6144 + nd] = (float)acc;
}

// ---------------------------------------------------------------------------
// Combine partials, write pos_new, mom_new, lmd.  grid (208) x 256
__global__ void k_out(const float* __restrict__ pos, const float* __restrict__ mom,
                      const float* __restrict__ mas, const float* __restrict__ dtm,
                      const float* __restrict__ ws, float* __restrict__ out)
{
    const int wg = blockIdx.x, t = threadIdx.x;
    if (wg < 192){
        const int b = wg / 24, nb = wg % 24;
        const int nd = nb*256 + t;
        float sacc = 0.f;
        for (int kc = 0; kc < 8; ++kc) sacc += ws[PART_OFF + ((size_t)kc*8 + b)*6144 + nd];
        const float frc = -sacc;
        const int n = nd / 3;
        const float dt = dtm[b], dt2 = dt*dt;
        out[(size_t)b*6144 + nd]         = pos[(size_t)b*6144 + nd] + frc / mas[b*NN + n] * dt2;
        out[49152 + (size_t)b*6144 + nd] = mom[(size_t)b*6144 + nd] + frc * dt;
    } else {
        const int idx = (wg - 192)*256 + t;      // 0..4095
        out[98304 + idx] = (float)(((const double*)(ws + LMD_OFF))[idx]);
    }
}

// ---------------------------------------------------------------------------
extern "C" void kernel_launch(void* const* d_in, const int* in_sizes, int n_in,
                              void* d_out, int out_size, void* d_ws, size_t ws_size,
                              hipStream_t stream)
{
    (void)in_sizes; (void)n_in; (void)out_size; (void)ws_size;
    const float* pos  = (const float*)d_in[0];
    const float* mom  = (const float*)d_in[1];
    const float* mas  = (const float*)d_in[2];
    const float* dtm  = (const float*)d_in[3];
    const float* jacp = (const float*)d_in[4];
    const int*   pi   = (const int*)d_in[5];
    const int*   pj   = (const int*)d_in[6];
    const float* d0v  = (const float*)d_in[7];
    float* ws  = (float*)d_ws;
    float* out = (float*)d_out;

    k_gbuild<<<dim3(CC, BB), 256, 0, stream>>>(pos, mas, jacp, pi, pj, ws);
    for (int it = 0; it < NITER; ++it){
        k_build<<<dim3(CC, BB), 256, 0, stream>>>(d0v, dtm, ws);
        for (int kb = 0; kb < 8; ++kb){
            k_panel<<<dim3(BB), 512, 0, stream>>>(ws, kb);
            k_apply<<<dim3(2*(7-kb)+1, BB), 256, 0, stream>>>(ws, kb);
            if (kb < 7)
                k_gemm<<<dim3(7-kb, 8-kb, BB), 256, 0, stream>>>(ws, kb);
        }
        k_backsub<<<dim3(BB), 256, 0, stream>>>(ws);
    }
    k_frc<<<dim3(24, BB, 8), 256, 0, stream>>>(jacp, ws);
    k_out<<<dim3(208), 256, 0, stream>>>(pos, mom, mas, dtm, ws, out);
}

// Round 6
// 5131.446 us; speedup vs baseline: 4.1905x; 1.1391x over previous
//
#include <hip/hip_runtime.h>
#include <cmath>

#define BB 8
#define NN 2048
#define CC 512
#define NITER 3
#define NREFINE 2
#define MP 516      // f64 matrix row stride (elements)
#define MP4 520     // f32 factor row stride (elements)
#define AUGCOL 512

// workspace layout (units: floats); f64 regions 8B-aligned (even offsets)
static constexpr size_t G_OFF   = 0;                         // f32 [B][3][C][C]
static constexpr size_t G_SZ    = (size_t)BB*3*CC*CC;        // 6291456
static constexpr size_t M64_OFF = G_OFF + G_SZ;              // f64 [B][C][MP] jac+con
static constexpr size_t M64_SZF = (size_t)BB*CC*MP*2;        // 4227072
static constexpr size_t F32_OFF = M64_OFF + M64_SZF;         // f32 [B][C][MP4] factors
static constexpr size_t F32_SZ  = (size_t)BB*CC*MP4;         // 2129920
static constexpr size_t T32_OFF = F32_OFF + F32_SZ;          // f32 scratch (permuted rows)
static constexpr size_t DF_OFF  = T32_OFF + F32_SZ;          // f64 [B][C][3]
static constexpr size_t DF_SZF  = (size_t)BB*CC*3*2;
static constexpr size_t LMD_OFF = DF_OFF + DF_SZF;           // f64 [B][C]
static constexpr size_t LMD_SZF = (size_t)BB*CC*2;
static constexpr size_t X0_OFF  = LMD_OFF + LMD_SZF;         // f64 [B][C] newton delta
static constexpr size_t X0_SZF  = (size_t)BB*CC*2;
static constexpr size_t R64_OFF = X0_OFF + X0_SZF;           // f64 [B][C] residual
static constexpr size_t R64_SZF = (size_t)BB*CC*2;
static constexpr size_t PERM_OFF= R64_OFF + R64_SZF;         // int [B][8][C] per-panel perms
static constexpr size_t PERM_SZ = (size_t)BB*8*CC;
static constexpr size_t PART_OFF= PERM_OFF + PERM_SZ;        // f32 [8][B][6144]

// ---------------------------------------------------------------------------
// G (f32, f64 math); diff0 (f64); zero lambda.   grid (512 c, 8 b) x 256
__global__ void k_gbuild(const float* __restrict__ pos, const float* __restrict__ mas,
                         const float* __restrict__ jacp, const int* __restrict__ pi,
                         const int* __restrict__ pj, float* __restrict__ ws)
{
    const int c = blockIdx.x, b = blockIdx.y, t = threadIdx.x;
    const int i = pi[c], j = pj[c];
    const double im = 1.0 / (double)mas[b*NN + i];
    const double jm = 1.0 / (double)mas[b*NN + j];
    float* G = ws + G_OFF;
    const float* Ji = jacp + ((size_t)b*CC*NN + i)*3;
    const float* Jj = jacp + ((size_t)b*CC*NN + j)*3;
    for (int cp = t; cp < CC; cp += 256){
        const size_t o = (size_t)cp*NN*3;
        const size_t gb = ((size_t)(b*3+0)*CC + c)*CC + cp;
        G[gb]                   = (float)((double)Ji[o+0]*im - (double)Jj[o+0]*jm);
        G[gb + (size_t)CC*CC]   = (float)((double)Ji[o+1]*im - (double)Jj[o+1]*jm);
        G[gb + (size_t)2*CC*CC] = (float)((double)Ji[o+2]*im - (double)Jj[o+2]*jm);
    }
    if (t == 0){
        double* df = (double*)(ws + DF_OFF) + ((size_t)b*CC + c)*3;
        for (int d = 0; d < 3; ++d)
            df[d] = (double)pos[((size_t)b*NN+i)*3+d] - (double)pos[((size_t)b*NN+j)*3+d];
    }
    if (c == 0){
        double* l = (double*)(ws + LMD_OFF) + (size_t)b*CC;
        l[t] = 0.0; l[t+256] = 0.0;
    }
}

// ---------------------------------------------------------------------------
// Assemble jac row (f64 into M64, f32 copy into F32) + con into aug cols.
// grid (512 c, 8 b) x 256
__global__ void k_build(const float* __restrict__ d0v, const float* __restrict__ dtm,
                        float* __restrict__ ws)
{
    const int c = blockIdx.x, b = blockIdx.y, t = threadIdx.x;
    const float* G = ws + G_OFF;
    const double* l = (const double*)(ws + LMD_OFF) + (size_t)b*CC;
    const double dt = (double)dtm[b], dt2 = dt*dt;
    const size_t g0 = ((size_t)(b*3+0)*CC + c)*CC;
    const size_t g1 = g0 + (size_t)CC*CC;
    const size_t g2 = g0 + (size_t)2*CC*CC;
    const int c1 = t, c2 = t + 256;
    const double l1 = l[c1], l2 = l[c2];
    const double ga0 = (double)G[g0+c1], gb0 = (double)G[g0+c2];
    const double ga1 = (double)G[g1+c1], gb1 = (double)G[g1+c2];
    const double ga2 = (double)G[g2+c1], gb2 = (double)G[g2+c2];
    double p0 = ga0*l1 + gb0*l2;
    double p1 = ga1*l1 + gb1*l2;
    double p2 = ga2*l1 + gb2*l2;
    __shared__ double red[12];
    #pragma unroll
    for (int off = 32; off; off >>= 1){
        p0 += __shfl_xor(p0, off);
        p1 += __shfl_xor(p1, off);
        p2 += __shfl_xor(p2, off);
    }
    if ((t & 63) == 0){ const int w = t>>6; red[w*3+0]=p0; red[w*3+1]=p1; red[w*3+2]=p2; }
    __syncthreads();
    const double y0 = red[0]+red[3]+red[6]+red[9];
    const double y1 = red[1]+red[4]+red[7]+red[10];
    const double y2 = red[2]+red[5]+red[8]+red[11];
    const double* df = (const double*)(ws + DF_OFF) + ((size_t)b*CC + c)*3;
    const double e0 = df[0] - dt2*y0;
    const double e1 = df[1] - dt2*y1;
    const double e2 = df[2] - dt2*y2;
    const double s = -2.0*dt2;
    const double j1 = s*(e0*ga0 + e1*ga1 + e2*ga2);
    const double j2 = s*(e0*gb0 + e1*gb1 + e2*gb2);
    double* Mrow = (double*)(ws + M64_OFF) + ((size_t)b*CC + c)*MP;
    float*  Frow = ws + F32_OFF + ((size_t)b*CC + c)*MP4;
    Mrow[c1] = j1; Mrow[c2] = j2;
    Frow[c1] = (float)j1; Frow[c2] = (float)j2;
    if (t == 0){
        const double con = e0*e0 + e1*e1 + e2*e2 - (double)d0v[c];
        Mrow[AUGCOL] = con; Frow[AUGCOL] = (float)con;
    }
}

// ---------------------------------------------------------------------------
// One f32 pivoted-elimination step, K compile-time (template-unrolled so all
// r[] indices are static). Logical row swaps via mypos. 2 barriers/step.
template<int K>
__device__ __forceinline__ void panel_step(float (&r)[64], int& mypos, const bool h,
                                           const int t, float* __restrict__ bufB,
                                           float* __restrict__ wv, int* __restrict__ wi,
                                           int* __restrict__ sh_lw)
{
    const float v = (h && mypos >= K) ? fabsf(r[K]) : -1.0f;
    float vmax = v;
    #pragma unroll
    for (int off = 32; off; off >>= 1){
        const float o = __shfl_xor(vmax, off);
        vmax = fmaxf(vmax, o);
    }
    int idx = (v >= 0.0f && v == vmax) ? t : (1 << 20);
    #pragma unroll
    for (int off = 32; off; off >>= 1){
        const int o = __shfl_xor(idx, off);
        idx = min(idx, o);
    }
    if ((t & 63) == 0){ wv[t>>6] = vmax; wi[t>>6] = idx; }
    __syncthreads();                                   // B1
    float gv = wv[0];
    #pragma unroll
    for (int w = 1; w < 8; ++w) gv = fmaxf(gv, wv[w]);
    int wp = 1 << 20;
    #pragma unroll
    for (int w = 0; w < 8; ++w) if (wv[w] == gv) wp = min(wp, wi[w]);
    if (t == wp){
        *sh_lw = mypos;
        #pragma unroll
        for (int j = K; j < 64; ++j) bufB[j] = r[j];
    }
    __syncthreads();                                   // B2
    const int lw = *sh_lw;
    if (t == wp) mypos = K;
    else if (mypos == K) mypos = lw;
    if (h && mypos > K){
        const float pv = bufB[K];
        const float ml = r[K] / pv;
        r[K] = ml;
        #pragma unroll
        for (int j = K + 1; j < 64; ++j) r[j] = fmaf(-ml, bufB[j], r[j]);
    }
}

template<int K>
__device__ __forceinline__ void panel_rec(float (&r)[64], int& mypos, const bool h,
                                          const int t, float* __restrict__ bufB,
                                          float* __restrict__ wv, int* __restrict__ wi,
                                          int* __restrict__ sh_lw)
{
    if constexpr (K < 64){
        panel_step<K>(r, mypos, h, t, bufB, wv, wi, sh_lw);
        panel_rec<K + 1>(r, mypos, h, t, bufB, wv, wi, sh_lw);
    }
}

// f32 panel factorization (partial pivoting, one row/thread). Stores factor
// rows scattered to pivoted order and this panel's perm slice.
// grid (8 b) x 512
__global__ __launch_bounds__(512, 2) void k_panel(float* __restrict__ ws, int kb)
{
    const int b = blockIdx.x, t = threadIdx.x;
    const int m = CC - kb*64, base = kb*64;
    float* F = ws + F32_OFF + (size_t)b*CC*MP4;

    __shared__ float bufB[64];
    __shared__ float wv[8];
    __shared__ int   wi[8];
    __shared__ int   sh_lw;

    const bool h = (t < m);
    float r[64];
    if (h){
        const float* sp = F + (size_t)(base + t)*MP4 + base;
        #pragma unroll
        for (int j = 0; j < 64; ++j) r[j] = sp[j];
    }
    int mypos = t;
    __syncthreads();

    panel_rec<0>(r, mypos, h, t, bufB, wv, wi, &sh_lw);

    if (h){
        float* dp = F + (size_t)(base + mypos)*MP4 + base;
        #pragma unroll
        for (int j = 0; j < 64; ++j) dp[j] = r[j];
        ((int*)(ws + PERM_OFF))[(b*8 + kb)*CC + mypos] = t;
    }
}

// ---------------------------------------------------------------------------
// Per 64-col stripe: permute U12 rows to LDS + below-panel rows to T32, then
// TRSM (unit-lower forward substitution), write U12 back.
// grid (8-kb stripes, 8 b) x 256;  sx==7-kb is the aug stripe (W=1)
__global__ __launch_bounds__(256) void k_apply(float* __restrict__ ws, int kb)
{
    const int sx = blockIdx.x, b = blockIdx.y, t = threadIdx.x;
    const int nfull = 7 - kb;
    const bool isaug = (sx == nfull);
    const int cs = isaug ? AUGCOL : (kb+1+sx)*64;
    const int W  = isaug ? 1 : 64;
    const int m = CC - kb*64, base = kb*64;
    float* F = ws + F32_OFF + (size_t)b*CC*MP4;
    float* T = ws + T32_OFF + (size_t)b*CC*MP4;
    const int* perm = (const int*)(ws + PERM_OFF) + (b*8 + kb)*CC;

    __shared__ float LT[64][65];   // LT[s][i] = L[i][s]
    __shared__ float Bs[64][65];

    for (int idx = t; idx < 4096; idx += 256){
        const int i = idx >> 6, s = idx & 63;
        LT[s][i] = F[(size_t)(base+i)*MP4 + base + s];
    }
    const int c = t & 63, rg = t >> 6;
    for (int l = rg; l < 64; l += 4)
        Bs[l][c] = (c < W) ? F[(size_t)(base + perm[l])*MP4 + cs + c] : 0.f;
    for (int l = 64 + rg; l < m; l += 4)
        if (c < W) T[(size_t)(base+l)*MP4 + cs + c] = F[(size_t)(base+perm[l])*MP4 + cs + c];
    __syncthreads();

    for (int s = 0; s < 63; ++s){
        const float bsc = Bs[s][c];
        #pragma unroll
        for (int i0 = 0; i0 < 16; ++i0){
            const int i = i0*4 + rg;
            if (i > s) Bs[i][c] = fmaf(-LT[s][i], bsc, Bs[i][c]);
        }
        __syncthreads();
    }

    for (int l = rg; l < 64; l += 4)
        if (c < W) F[(size_t)(base+l)*MP4 + cs + c] = Bs[l][c];
}

// ---------------------------------------------------------------------------
// Trailing update: F[rows][stripe] = T[rows][stripe] - L21*U12 (f32, K=64)
// grid (7-kb rt, 8-kb sx, 8 b) x 256
__global__ __launch_bounds__(256) void k_gemm(float* __restrict__ ws, int kb)
{
    const int rt = blockIdx.x, sx = blockIdx.y, b = blockIdx.z, t = threadIdx.x;
    const int nfull = 7 - kb;
    const bool isaug = (sx == nfull);
    const int cs = isaug ? AUGCOL : (kb+1+sx)*64;
    const int W  = isaug ? 1 : 64;
    const int base = kb*64;
    const int gr0 = base + 64 + rt*64;
    float* F = ws + F32_OFF + (size_t)b*CC*MP4;
    float* T = ws + T32_OFF + (size_t)b*CC*MP4;

    __shared__ float LTc[64][67];  // LTc[kk][r] = L21[gr0+r][base+kk]
    __shared__ float Uc [64][67];  // Uc[kk][c]  = U12[base+kk][cs+c]

    for (int idx = t; idx < 4096; idx += 256){
        const int r = idx >> 6, kk = idx & 63;
        LTc[kk][r] = F[(size_t)(gr0+r)*MP4 + base + kk];
    }
    for (int idx = t; idx < 4096; idx += 256){
        const int rr2 = idx >> 6, cc2 = idx & 63;
        Uc[rr2][cc2] = (cc2 < W) ? F[(size_t)(base + rr2)*MP4 + cs + cc2] : 0.f;
    }
    __syncthreads();

    const int rq = t >> 4, cq = t & 15;
    float acc[4][4] = {};
    for (int kk = 0; kk < 64; ++kk){
        const float lv0 = LTc[kk][rq*4+0], lv1 = LTc[kk][rq*4+1];
        const float lv2 = LTc[kk][rq*4+2], lv3 = LTc[kk][rq*4+3];
        const float uv0 = Uc[kk][cq*4+0], uv1 = Uc[kk][cq*4+1];
        const float uv2 = Uc[kk][cq*4+2], uv3 = Uc[kk][cq*4+3];
        acc[0][0]=fmaf(lv0,uv0,acc[0][0]); acc[0][1]=fmaf(lv0,uv1,acc[0][1]);
        acc[0][2]=fmaf(lv0,uv2,acc[0][2]); acc[0][3]=fmaf(lv0,uv3,acc[0][3]);
        acc[1][0]=fmaf(lv1,uv0,acc[1][0]); acc[1][1]=fmaf(lv1,uv1,acc[1][1]);
        acc[1][2]=fmaf(lv1,uv2,acc[1][2]); acc[1][3]=fmaf(lv1,uv3,acc[1][3]);
        acc[2][0]=fmaf(lv2,uv0,acc[2][0]); acc[2][1]=fmaf(lv2,uv1,acc[2][1]);
        acc[2][2]=fmaf(lv2,uv2,acc[2][2]); acc[2][3]=fmaf(lv2,uv3,acc[2][3]);
        acc[3][0]=fmaf(lv3,uv0,acc[3][0]); acc[3][1]=fmaf(lv3,uv1,acc[3][1]);
        acc[3][2]=fmaf(lv3,uv2,acc[3][2]); acc[3][3]=fmaf(lv3,uv3,acc[3][3]);
    }
    #pragma unroll
    for (int i = 0; i < 4; ++i)
        #pragma unroll
        for (int j = 0; j < 4; ++j){
            const int c2 = cq*4 + j;
            if (c2 < W){
                const size_t o = (size_t)(gr0 + rq*4 + i)*MP4 + cs + c2;
                F[o] = T[o] - acc[i][j];
            }
        }
}

// ---------------------------------------------------------------------------
// f32 back-substitution on U with the eliminated aug column -> X0 (f64).
// grid (8 b) x 256
__global__ __launch_bounds__(256) void k_backsub(float* __restrict__ ws)
{
    const int b = blockIdx.x, t = threadIdx.x;
    float* F = ws + F32_OFF + (size_t)b*CC*MP4;
    __shared__ float y[CC];
    __shared__ float Ud[64][65];
    y[t]     = F[(size_t)t*MP4 + AUGCOL];
    y[t+256] = F[(size_t)(t+256)*MP4 + AUGCOL];
    __syncthreads();
    for (int sb = 7; sb >= 0; --sb){
        const int rb = sb*64;
        for (int idx = t; idx < 4096; idx += 256)
            Ud[idx>>6][idx&63] = F[(size_t)(rb + (idx>>6))*MP4 + rb + (idx&63)];
        __syncthreads();
        if (t < 64){
            float yv = y[rb + t];
            for (int kk = 63; kk >= 0; --kk){
                float xk = __shfl(yv, kk);
                xk = xk / Ud[kk][kk];
                if (t == kk) yv = xk;
                else if (t < kk) yv = fmaf(-Ud[t][kk], xk, yv);
            }
            y[rb + t] = yv;
        }
        __syncthreads();
        for (int r = t; r < rb; r += 256){
            const float* Fr = F + (size_t)r*MP4 + rb;
            float sacc = 0.f;
            for (int j = 0; j < 64; ++j) sacc = fmaf(Fr[j], y[rb + j], sacc);
            y[r] -= sacc;
        }
        __syncthreads();
    }
    double* x0 = (double*)(ws + X0_OFF) + (size_t)b*CC;
    x0[t]     = (double)y[t];
    x0[t+256] = (double)y[t+256];
}

// ---------------------------------------------------------------------------
// f64 residual: R64 = con - A64 @ x0.   grid (512 c, 8 b) x 256
__global__ void k_resid(float* __restrict__ ws)
{
    const int c = blockIdx.x, b = blockIdx.y, t = threadIdx.x;
    const double* Mrow = (const double*)(ws + M64_OFF) + ((size_t)b*CC + c)*MP;
    const double* x0 = (const double*)(ws + X0_OFF) + (size_t)b*CC;
    double p = Mrow[t]*x0[t] + Mrow[t+256]*x0[t+256];
    __shared__ double red[4];
    #pragma unroll
    for (int off = 32; off; off >>= 1) p += __shfl_xor(p, off);
    if ((t & 63) == 0) red[t>>6] = p;
    __syncthreads();
    if (t == 0)
        ((double*)(ws + R64_OFF))[b*CC + c] = Mrow[AUGCOL] - (red[0]+red[1]+red[2]+red[3]);
}

// ---------------------------------------------------------------------------
// Refinement solve with stored f32 factors: d = U^-1 L^-1 P r; X0 += d;
// if final: lmd -= X0.   grid (8 b) x 512
__global__ __launch_bounds__(512) void k_rsolve(float* __restrict__ ws, int final_)
{
    const int b = blockIdx.x, t = threadIdx.x;
    const float* F = ws + F32_OFF + (size_t)b*CC*MP4;
    __shared__ float y[CC];
    __shared__ float Ls[64][65];
    y[t] = (float)((const double*)(ws + R64_OFF))[b*CC + t];
    __syncthreads();
    // forward: replay per-panel permutation + unit-L solve + L21 GEMV
    for (int kb = 0; kb < 8; ++kb){
        const int base = kb*64, m = CC - base;
        const int* perm = (const int*)(ws + PERM_OFF) + (b*8 + kb)*CC;
        float v = 0.f;
        if (t < m) v = y[base + perm[t]];
        __syncthreads();
        if (t < m) y[base + t] = v;
        for (int idx = t; idx < 4096; idx += 512)
            Ls[idx>>6][idx&63] = F[(size_t)(base + (idx>>6))*MP4 + base + (idx&63)];
        __syncthreads();
        if (t < 64){
            float yv = y[base + t];
            for (int kk = 0; kk < 63; ++kk){
                const float xk = __shfl(yv, kk);
                if (t > kk) yv = fmaf(-Ls[t][kk], xk, yv);
            }
            y[base + t] = yv;
        }
        __syncthreads();
        if (t >= 64 && t < m){
            const float* Fr = F + (size_t)(base + t)*MP4 + base;
            float sacc = 0.f;
            for (int s = 0; s < 64; ++s) sacc = fmaf(Fr[s], y[base + s], sacc);
            y[base + t] -= sacc;
        }
        __syncthreads();
    }
    // backward: U solve
    for (int sb = 7; sb >= 0; --sb){
        const int rb = sb*64;
        for (int idx = t; idx < 4096; idx += 512)
            Ls[idx>>6][idx&63] = F[(size_t)(rb + (idx>>6))*MP4 + rb + (idx&63)];
        __syncthreads();
        if (t < 64){
            float yv = y[rb + t];
            for (int kk = 63; kk >= 0; --kk){
                float xk = __shfl(yv, kk);
                xk = xk / Ls[kk][kk];
                if (t == kk) yv = xk;
                else if (t < kk) yv = fmaf(-Ls[t][kk], xk, yv);
            }
            y[rb + t] = yv;
        }
        __syncthreads();
        if (t < rb){
            const float* Fr = F + (size_t)t*MP4 + rb;
            float sacc = 0.f;
            for (int j = 0; j < 64; ++j) sacc = fmaf(Fr[j], y[rb + j], sacc);
            y[t] -= sacc;
        }
        __syncthreads();
    }
    double* x0 = (double*)(ws + X0_OFF) + (size_t)b*CC;
    const double nx = x0[t] + (double)y[t];
    x0[t] = nx;
    if (final_){
        double* l = (double*)(ws + LMD_OFF) + (size_t)b*CC;
        l[t] -= nx;
    }
}

// ---------------------------------------------------------------------------
// Split-K partial of sum_c lmd*jacp (f64 accum, f32 store).
// grid (24 nb, 8 b, 8 kc) x 256
__global__ void k_frc(const float* __restrict__ jacp, float* __restrict__ ws)
{
    const int nb = blockIdx.x, b = blockIdx.y, kc = blockIdx.z, t = threadIdx.x;
    const int nd = nb*256 + t;
    const double* l = (const double*)(ws + LMD_OFF) + (size_t)b*CC + kc*64;
    const float* J = jacp + ((size_t)(b*CC + kc*64))*NN*3 + nd;
    double acc = 0.0;
    for (int c2 = 0; c2 < 64; ++c2) acc = fma(l[c2], (double)J[(size_t)c2*NN*3], acc);
    ws[PART_OFF + ((size_t)kc*8 + b)*6144 + nd] = (float)acc;
}

// ---------------------------------------------------------------------------
// Combine partials, write pos_new, mom_new, lmd.  grid (208) x 256
__global__ void k_out(const float* __restrict__ pos, const float* __restrict__ mom,
                      const float* __restrict__ mas, const float* __restrict__ dtm,
                      const float* __restrict__ ws, float* __restrict__ out)
{
    const int wg = blockIdx.x, t = threadIdx.x;
    if (wg < 192){
        const int b = wg / 24, nb = wg % 24;
        const int nd = nb*256 + t;
        float sacc = 0.f;
        for (int kc = 0; kc < 8; ++kc) sacc += ws[PART_OFF + ((size_t)kc*8 + b)*6144 + nd];
        const float frc = -sacc;
        const int n = nd / 3;
        const float dt = dtm[b], dt2 = dt*dt;
        out[(size_t)b*6144 + nd]         = pos[(size_t)b*6144 + nd] + frc / mas[b*NN + n] * dt2;
        out[49152 + (size_t)b*6144 + nd] = mom[(size_t)b*6144 + nd] + frc * dt;
    } else {
        const int idx = (wg - 192)*256 + t;      // 0..4095
        out[98304 + idx] = (float)(((const double*)(ws + LMD_OFF))[idx]);
    }
}

// ---------------------------------------------------------------------------
extern "C" void kernel_launch(void* const* d_in, const int* in_sizes, int n_in,
                              void* d_out, int out_size, void* d_ws, size_t ws_size,
                              hipStream_t stream)
{
    (void)in_sizes; (void)n_in; (void)out_size; (void)ws_size;
    const float* pos  = (const float*)d_in[0];
    const float* mom  = (const float*)d_in[1];
    const float* mas  = (const float*)d_in[2];
    const float* dtm  = (const float*)d_in[3];
    const float* jacp = (const float*)d_in[4];
    const int*   pi   = (const int*)d_in[5];
    const int*   pj   = (const int*)d_in[6];
    const float* d0v  = (const float*)d_in[7];
    float* ws  = (float*)d_ws;
    float* out = (float*)d_out;

    k_gbuild<<<dim3(CC, BB), 256, 0, stream>>>(pos, mas, jacp, pi, pj, ws);
    for (int it = 0; it < NITER; ++it){
        k_build<<<dim3(CC, BB), 256, 0, stream>>>(d0v, dtm, ws);
        for (int kb = 0; kb < 8; ++kb){
            k_panel<<<dim3(BB), 512, 0, stream>>>(ws, kb);
            k_apply<<<dim3(8 - kb, BB), 256, 0, stream>>>(ws, kb);
            if (kb < 7)
                k_gemm<<<dim3(7 - kb, 8 - kb, BB), 256, 0, stream>>>(ws, kb);
        }
        k_backsub<<<dim3(BB), 256, 0, stream>>>(ws);
        for (int rf = 0; rf < NREFINE; ++rf){
            k_resid<<<dim3(CC, BB), 256, 0, stream>>>(ws);
            k_rsolve<<<dim3(BB), 512, 0, stream>>>(ws, rf == NREFINE - 1 ? 1 : 0);
        }
    }
    k_frc<<<dim3(24, BB, 8), 256, 0, stream>>>(jacp, ws);
    k_out<<<dim3(208), 256, 0, stream>>>(pos, mom, mas, dtm, ws, out);
}